// Round 10
// baseline (6182.040 us; speedup 1.0000x reference)
//
#include <hip/hip_runtime.h>
#include <hip/hip_bf16.h>

typedef __hip_bfloat16 bf16;
typedef __attribute__((ext_vector_type(8))) __bf16 bf16x8;
typedef __attribute__((ext_vector_type(4))) float f32x4;
typedef __attribute__((ext_vector_type(4))) unsigned int u32x4;

#define DEVI __device__ __forceinline__

DEVI float sigm(float x) { return 1.f / (1.f + __expf(-x)); }
DEVI float tanh_fast(float x) { float e = __expf(2.f * x); return 1.f - 2.f / (e + 1.f); }
DEVI float lo2f(unsigned u) { return __uint_as_float(u << 16); }
DEVI float hi2f(unsigned u) { return __uint_as_float(u & 0xffff0000u); }

DEVI __bf16 f2b(float f) {               // RNE f32->bf16
    unsigned u = __float_as_uint(f);
    u = u + 0x7FFFu + ((u >> 16) & 1u);
    unsigned short s = (unsigned short)(u >> 16);
    __bf16 b;
    __builtin_memcpy(&b, &s, 2);
    return b;
}
DEVI unsigned short b2u(__bf16 b) { unsigned short s; __builtin_memcpy(&s, &b, 2); return s; }

DEVI f32x4 MFMA(bf16x8 a, bf16x8 b, f32x4 c) {
    return __builtin_amdgcn_mfma_f32_16x16x32_bf16(a, b, c, 0, 0, 0);
}

DEVI bf16x8 load8(const bf16* p) { return *reinterpret_cast<const bf16x8*>(p); }
DEVI bf16x8 load8(const float* p) {
    float4 a = *reinterpret_cast<const float4*>(p);
    float4 b = *reinterpret_cast<const float4*>(p + 4);
    bf16x8 r;
    r[0] = f2b(a.x); r[1] = f2b(a.y); r[2] = f2b(a.z); r[3] = f2b(a.w);
    r[4] = f2b(b.x); r[5] = f2b(b.y); r[6] = f2b(b.z); r[7] = f2b(b.w);
    return r;
}

DEVI void storeOut(float* p, float v) { *p = v; }
DEVI void storeOut(bf16* p, float v) { *p = __float2bfloat16(v); }

// ---- coherent (cache-bypassing) memory ops via asm sc0 sc1 -----------------
#define WAIT_COHERENT() do { \
    asm volatile("s_waitcnt vmcnt(0)" ::: "memory"); \
    __builtin_amdgcn_sched_barrier(0); } while (0)

DEVI bf16x8 ld_cv16(const bf16* p) {
    u32x4 r;
    asm volatile("global_load_dwordx4 %0, %1, off sc0 sc1"
                 : "=v"(r) : "v"(p) : "memory");
    bf16x8 out;
    __builtin_memcpy(&out, &r, 16);
    return out;
}
DEVI f32x4 ld_cv16f(const float* p) {
    f32x4 r;
    asm volatile("global_load_dwordx4 %0, %1, off sc0 sc1"
                 : "=v"(r) : "v"(p) : "memory");
    return r;
}
DEVI unsigned ld_c_u32(const void* p) {
    unsigned r;
    asm volatile("global_load_dword %0, %1, off sc0 sc1"
                 : "=v"(r) : "v"(p) : "memory");
    return r;
}
DEVI void st_c_u32(void* p, unsigned v) {
    asm volatile("global_store_dword %0, %1, off sc0 sc1"
                 :: "v"(p), "v"(v) : "memory");
}

// Grid barrier: drain own vmem (incl. asm coherent stores), then flag.
DEVI void gsync(unsigned* bar, unsigned target) {
    asm volatile("s_waitcnt vmcnt(0)" ::: "memory");
    __syncthreads();
    if (threadIdx.x == 0) {
        __hip_atomic_fetch_add(bar, 1u, __ATOMIC_RELAXED, __HIP_MEMORY_SCOPE_AGENT);
        while (atomicAdd(bar, 0u) < target) __builtin_amdgcn_s_sleep(1);
    }
    asm volatile("" ::: "memory");
    __syncthreads();
}

// ---------------------------------------------------------------------------
// Generic MFMA GEMM: C[m*crs + n*ccs] = sum_k A[m,k]*B[n,k] (+bias[n]).
// ---------------------------------------------------------------------------
template<typename AT, typename BT, typename OT, bool GATHER, bool HASB>
__global__ __launch_bounds__(256)
void gemm_bt(const AT* __restrict__ A, const int* __restrict__ Aidx, int lda,
             const BT* __restrict__ B, int ldb, int boff,
             const float* __restrict__ bias,
             OT* __restrict__ C, long crs, long ccs,
             int M_real, int K)
{
    __shared__ __attribute__((aligned(16))) bf16 As[128 * 32];
    __shared__ __attribute__((aligned(16))) bf16 Bs[128 * 32];
    const int tid = threadIdx.x;
    const int lane = tid & 63;
    const int w = tid >> 6;
    const int wr = w >> 1, wc = w & 1;
    const int bm = blockIdx.y * 128;
    const int bn = blockIdx.x * 128;

    const int l16_0 = (2 * w + 0) * 64 + lane;
    const int l16_1 = (2 * w + 1) * 64 + lane;
    const int row0 = l16_0 >> 2, c0 = l16_0 & 3;
    const int row1 = l16_1 >> 2, c1 = l16_1 & 3;

    long arow0 = GATHER ? (long)Aidx[bm + row0] : (long)(bm + row0);
    long arow1 = GATHER ? (long)Aidx[bm + row1] : (long)(bm + row1);
    const AT* agp0 = A + arow0 * lda + c0 * 8;
    const AT* agp1 = A + arow1 * lda + c1 * 8;
    const BT* bgp0 = B + (long)(bn + row0) * ldb + boff + c0 * 8;
    const BT* bgp1 = B + (long)(bn + row1) * ldb + boff + c1 * 8;

    f32x4 acc[4][4];
    #pragma unroll
    for (int i = 0; i < 4; i++)
        #pragma unroll
        for (int j = 0; j < 4; j++) acc[i][j] = f32x4{0.f, 0.f, 0.f, 0.f};

    const bf16x8* Asv = reinterpret_cast<const bf16x8*>(As);
    const bf16x8* Bsv = reinterpret_cast<const bf16x8*>(Bs);
    bf16x8* AsW = reinterpret_cast<bf16x8*>(As);
    bf16x8* BsW = reinterpret_cast<bf16x8*>(Bs);
    const int kq = lane >> 4;
    const int lrow = lane & 15;

    bf16x8 ra0 = load8(agp0);
    bf16x8 ra1 = load8(agp1);
    bf16x8 rb0 = load8(bgp0);
    bf16x8 rb1 = load8(bgp1);

    for (int k0 = 0; k0 < K; k0 += 32) {
        __syncthreads();
        AsW[l16_0] = ra0; AsW[l16_1] = ra1;
        BsW[l16_0] = rb0; BsW[l16_1] = rb1;
        __syncthreads();

        const int kn = k0 + 32;
        if (kn < K) {
            ra0 = load8(agp0 + kn);
            ra1 = load8(agp1 + kn);
            rb0 = load8(bgp0 + kn);
            rb1 = load8(bgp1 + kn);
        }

        bf16x8 af[4], bfr[4];
        #pragma unroll
        for (int mt = 0; mt < 4; mt++) af[mt] = Asv[(wr * 64 + mt * 16 + lrow) * 4 + kq];
        #pragma unroll
        for (int nt = 0; nt < 4; nt++) bfr[nt] = Bsv[(wc * 64 + nt * 16 + lrow) * 4 + kq];
        #pragma unroll
        for (int mt = 0; mt < 4; mt++)
            #pragma unroll
            for (int nt = 0; nt < 4; nt++)
                acc[mt][nt] = MFMA(af[mt], bfr[nt], acc[mt][nt]);
    }

    const int rbase = kq * 4;
    #pragma unroll
    for (int nt = 0; nt < 4; nt++) {
        const int col = bn + wc * 64 + nt * 16 + lrow;
        float bv = 0.f;
        if (HASB) bv = bias[col];
        #pragma unroll
        for (int mt = 0; mt < 4; mt++) {
            const int rw = bm + wr * 64 + mt * 16 + rbase;
            #pragma unroll
            for (int r = 0; r < 4; r++) {
                const int row = rw + r;
                if (row < M_real) storeOut(&C[(long)row * crs + (long)col * ccs], acc[mt][nt][r] + bv);
            }
        }
    }
}

// ---------------------------------------------------------------------------
// FC GEMM (proven): logits = H_all @ fc_W_bf^T + fc_b, XCD panel mapping.
// ---------------------------------------------------------------------------
__global__ __launch_bounds__(256)
void gemm_fc(const bf16* __restrict__ A, const bf16* __restrict__ B,
             const float* __restrict__ bias, float* __restrict__ C)
{
    __shared__ __attribute__((aligned(16))) bf16 As[8192];
    __shared__ __attribute__((aligned(16))) bf16 Bs[8192];
    const int tid = threadIdx.x;
    const int bid = blockIdx.x;
    const int xcd = bid & 7;
    const int ii = bid >> 3;
    const int p = xcd + 8 * (ii >> 4);
    const int m = ii & 15;
    if (p >= 250) return;
    const int bm = m * 128, bn = p * 128;

    const int lane = tid & 63, w = tid >> 6, wr = w >> 1, wc = w & 1;
    const int kq = lane >> 4, lrow = lane & 15;

    int rowc[4], c8c[4];
    const bf16* gA[4];
    const bf16* gB[4];
    #pragma unroll
    for (int c = 0; c < 4; c++) {
        int q = c * 256 + tid;
        rowc[c] = q >> 3; c8c[c] = q & 7;
        gA[c] = A + (long)(bm + rowc[c]) * 1024 + c8c[c] * 8;
        gB[c] = B + (long)(bn + rowc[c]) * 1024 + c8c[c] * 8;
    }

    f32x4 acc[4][4];
    #pragma unroll
    for (int i = 0; i < 4; i++)
        #pragma unroll
        for (int j = 0; j < 4; j++) acc[i][j] = f32x4{0.f, 0.f, 0.f, 0.f};

    bf16x8* AsW = reinterpret_cast<bf16x8*>(As);
    bf16x8* BsW = reinterpret_cast<bf16x8*>(Bs);
    const bf16x8* Asv = reinterpret_cast<const bf16x8*>(As);
    const bf16x8* Bsv = reinterpret_cast<const bf16x8*>(Bs);

    bf16x8 ra[4], rb[4];
    #pragma unroll
    for (int c = 0; c < 4; c++) { ra[c] = load8(gA[c]); rb[c] = load8(gB[c]); }

    for (int kt = 0; kt < 16; ++kt) {
        __syncthreads();
        #pragma unroll
        for (int c = 0; c < 4; c++) {
            AsW[c8c[c] * 128 + rowc[c]] = ra[c];
            BsW[c8c[c] * 128 + rowc[c]] = rb[c];
        }
        __syncthreads();
        if (kt < 15) {
            const int ko = (kt + 1) * 64;
            #pragma unroll
            for (int c = 0; c < 4; c++) { ra[c] = load8(gA[c] + ko); rb[c] = load8(gB[c] + ko); }
        }
        #pragma unroll
        for (int h = 0; h < 2; ++h) {
            bf16x8 af[4], bfr[4];
            #pragma unroll
            for (int mt = 0; mt < 4; mt++) af[mt] = Asv[(h * 4 + kq) * 128 + wr * 64 + mt * 16 + lrow];
            #pragma unroll
            for (int nt = 0; nt < 4; nt++) bfr[nt] = Bsv[(h * 4 + kq) * 128 + wc * 64 + nt * 16 + lrow];
            #pragma unroll
            for (int mt = 0; mt < 4; mt++)
                #pragma unroll
                for (int nt = 0; nt < 4; nt++)
                    acc[mt][nt] = MFMA(af[mt], bfr[nt], acc[mt][nt]);
        }
    }

    const int rbase = kq * 4;
    #pragma unroll
    for (int nt = 0; nt < 4; nt++) {
        const int col = bn + wc * 64 + nt * 16 + lrow;
        const float bv = bias[col];
        #pragma unroll
        for (int mt = 0; mt < 4; mt++) {
            const int rw = bm + wr * 64 + mt * 16 + rbase;
            #pragma unroll
            for (int r = 0; r < 4; r++) {
                const int row = rw + r;
                if (row < 2016) C[(long)row * 32000 + col] = acc[mt][nt][r] + bv;
            }
        }
    }
}

// ---------------------------------------------------------------------------
__global__ __launch_bounds__(256)
void cvt_f32_bf16(const float* __restrict__ in, bf16* __restrict__ out, int n)
{
    int i = (blockIdx.x * blockDim.x + threadIdx.x) * 4;
    if (i < n) {
        float4 v = *reinterpret_cast<const float4*>(in + i);
        ushort4 o;
        o.x = b2u(f2b(v.x)); o.y = b2u(f2b(v.y));
        o.z = b2u(f2b(v.z)); o.w = b2u(f2b(v.w));
        *reinterpret_cast<ushort4*>(out + i) = o;
    }
}

// Whp[k8][e][8] = bf16(attn_W[e][k8*8 .. +8])  (k-major pack for coalesced a-dot)
__global__ __launch_bounds__(256)
void cvt_whp(const float* __restrict__ in, bf16* __restrict__ out)
{
    int t = blockIdx.x * blockDim.x + threadIdx.x;     // 65536
    if (t < 65536) {
        const int e = t >> 7;          // 0..511
        const int k8 = t & 127;        // 0..127
        const float* src = in + (size_t)e * 2048 + k8 * 8;
        float4 a = *reinterpret_cast<const float4*>(src);
        float4 b = *reinterpret_cast<const float4*>(src + 4);
        ushort4 o0, o1;
        o0.x = b2u(f2b(a.x)); o0.y = b2u(f2b(a.y));
        o0.z = b2u(f2b(a.z)); o0.w = b2u(f2b(a.w));
        o1.x = b2u(f2b(b.x)); o1.y = b2u(f2b(b.y));
        o1.z = b2u(f2b(b.z)); o1.w = b2u(f2b(b.w));
        bf16* dst = out + ((size_t)k8 * 512 + e) * 8;
        *reinterpret_cast<ushort4*>(dst) = o0;
        *reinterpret_cast<ushort4*>(dst + 4) = o1;
    }
}

// ---------------------------------------------------------------------------
// Persistent encoder (unchanged; ~6-8us/step with 1 barrier).
// ---------------------------------------------------------------------------
__global__ __launch_bounds__(512, 1)
void enc_persist(bf16* __restrict__ h_bf,
                 const float* __restrict__ X,
                 const bf16* __restrict__ Whh, const float* __restrict__ bhh,
                 bf16* __restrict__ enc_out,
                 unsigned* __restrict__ bar)
{
    __shared__ float part[8][3][32][33];
    const int tid = threadIdx.x;
    const int lane = tid & 63;
    const int kw = tid >> 6;
    const int lrow = lane & 15;
    const int kq = lane >> 4;
    const int j0 = blockIdx.x * 32;

    const bf16x8* wv = reinterpret_cast<const bf16x8*>(Whh);
    bf16x8 wB[3][2][4];
    #pragma unroll
    for (int g = 0; g < 3; g++)
        #pragma unroll
        for (int jt = 0; jt < 2; jt++)
            #pragma unroll
            for (int kk = 0; kk < 4; kk++)
                wB[g][jt][kk] = wv[(size_t)(g * 1024 + j0 + jt * 16 + lrow) * 128 + kw * 16 + kq + kk * 4];

    const int bb = tid >> 4;
    const int jp = tid & 15;
    float bh[3][2];
    #pragma unroll
    for (int g = 0; g < 3; g++) {
        bh[g][0] = bhh[g * 1024 + j0 + jp * 2];
        bh[g][1] = bhh[g * 1024 + j0 + jp * 2 + 1];
    }
    float hprev[2] = {0.f, 0.f};
    unsigned sn = 0;

    for (int t = 0; t < 64; ++t) {
        const int cur = t & 1;
        const bf16* hbuf = h_bf + cur * 32768;

        bf16x8 af[2][4];
        #pragma unroll
        for (int bt = 0; bt < 2; bt++)
            #pragma unroll
            for (int kk = 0; kk < 4; kk++)
                af[bt][kk] = ld_cv16(hbuf + ((size_t)(bt * 16 + lrow) * 128 + kw * 16 + kq + kk * 4) * 8);

        const size_t xb = ((size_t)bb * 64 + t) * 3072 + j0 + jp * 2;
        float2 xg0 = *reinterpret_cast<const float2*>(X + xb);
        float2 xg1 = *reinterpret_cast<const float2*>(X + xb + 1024);
        float2 xg2 = *reinterpret_cast<const float2*>(X + xb + 2048);
        WAIT_COHERENT();

        f32x4 acc[3][2][2];
        #pragma unroll
        for (int g = 0; g < 3; g++)
            #pragma unroll
            for (int jt = 0; jt < 2; jt++)
                #pragma unroll
                for (int bt = 0; bt < 2; bt++) acc[g][jt][bt] = f32x4{0, 0, 0, 0};
        #pragma unroll
        for (int kk = 0; kk < 4; kk++)
            #pragma unroll
            for (int g = 0; g < 3; g++)
                #pragma unroll
                for (int jt = 0; jt < 2; jt++) {
                    acc[g][jt][0] = MFMA(af[0][kk], wB[g][jt][kk], acc[g][jt][0]);
                    acc[g][jt][1] = MFMA(af[1][kk], wB[g][jt][kk], acc[g][jt][1]);
                }
        #pragma unroll
        for (int g = 0; g < 3; g++)
            #pragma unroll
            for (int jt = 0; jt < 2; jt++)
                #pragma unroll
                for (int bt = 0; bt < 2; bt++)
                    #pragma unroll
                    for (int r = 0; r < 4; r++)
                        part[kw][g][bt * 16 + kq * 4 + r][jt * 16 + lrow] = acc[g][jt][bt][r];
        __syncthreads();

        float h2o[2];
        #pragma unroll
        for (int o = 0; o < 2; ++o) {
            const int jc = jp * 2 + o;
            float s0 = 0.f, s1 = 0.f, s2 = 0.f;
            #pragma unroll
            for (int ww = 0; ww < 8; ww++) {
                s0 += part[ww][0][bb][jc];
                s1 += part[ww][1][bb][jc];
                s2 += part[ww][2][bb][jc];
            }
            float x0 = o ? xg0.y : xg0.x;
            float x1 = o ? xg1.y : xg1.x;
            float x2 = o ? xg2.y : xg2.x;
            float rr = sigm(x0 + s0 + bh[0][o]);
            float zz = sigm(x1 + s1 + bh[1][o]);
            float nn = tanh_fast(x2 + rr * (s2 + bh[2][o]));
            h2o[o] = (1.f - zz) * nn + zz * hprev[o];
            hprev[o] = h2o[o];
        }
        unsigned pk = (unsigned)b2u(f2b(h2o[0])) | ((unsigned)b2u(f2b(h2o[1])) << 16);
        st_c_u32(h_bf + (cur ^ 1) * 32768 + bb * 1024 + j0 + jp * 2, pk);
        *reinterpret_cast<unsigned*>(enc_out + ((size_t)bb * 64 + t) * 1024 + j0 + jp * 2) = pk;

        if (t < 63) gsync(bar, ++sn * 32);
    }
}

// ---------------------------------------------------------------------------
// Persistent decoder, round 10: TWO barriers/step.
//  A: coherent h-frags (af, reused in B) + own-batch h -> LDS;
//     a[:,b] computed LOCALLY via k-major Whp (coalesced L2 reads);
//     scores (coalesced enc_pj); softmax; publish w[b,:].  bar.
//  B: GRU MFMA (af) + ctx-dot on per-gate [m][j] encT; pointwise; publish h.
//     bar.
// ---------------------------------------------------------------------------
__global__ __launch_bounds__(512, 1)
void dec_persist(bf16* __restrict__ h_bf,
                 const float* __restrict__ X,
                 const bf16* __restrict__ Whh, const float* __restrict__ bhh,
                 const bf16* __restrict__ encT0,   // [2048 m][1024 j] per gate
                 const bf16* __restrict__ encT1,
                 const bf16* __restrict__ encT2,
                 bf16* __restrict__ Hall,
                 const bf16* __restrict__ Whp,     // [128 k8][512 e][8] bf16
                 const bf16* __restrict__ enc_pj,  // [2048 m][512 e] bf16
                 const float* __restrict__ v_w,
                 float* __restrict__ w_g,          // [32 b][64 s] f32
                 unsigned* __restrict__ bar)
{
    __shared__ float part[8][3][32][33];      // ~101 KB
    __shared__ __attribute__((aligned(16))) float hbl[1024];
    __shared__ __attribute__((aligned(16))) float a_ls[512];
    __shared__ __attribute__((aligned(16))) float w_s[2048];   // [32][64]
    __shared__ float sc_s[64];

    const int tid = threadIdx.x;
    const int lane = tid & 63;
    const int kw = tid >> 6;
    const int lrow = lane & 15;
    const int kq = lane >> 4;
    const int j0 = blockIdx.x * 32;
    const int b = blockIdx.x;                 // attention batch

    // hoisted Whh fragments (96 VGPR)
    const bf16x8* wv = reinterpret_cast<const bf16x8*>(Whh);
    bf16x8 wB[3][2][4];
    #pragma unroll
    for (int g = 0; g < 3; g++)
        #pragma unroll
        for (int jt = 0; jt < 2; jt++)
            #pragma unroll
            for (int kk = 0; kk < 4; kk++)
                wB[g][jt][kk] = wv[(size_t)(g * 1024 + j0 + jt * 16 + lrow) * 128 + kw * 16 + kq + kk * 4];

    // hoisted v_w chunk: e = lane*8 + ii
    float vr[8];
    #pragma unroll
    for (int ii = 0; ii < 8; ii++) vr[ii] = v_w[lane * 8 + ii];

    const int bb = tid >> 4;
    const int jp = tid & 15;
    float bh[3][2];
    #pragma unroll
    for (int g = 0; g < 3; g++) {
        bh[g][0] = bhh[g * 1024 + j0 + jp * 2];
        bh[g][1] = bhh[g * 1024 + j0 + jp * 2 + 1];
    }

    // seed hprev from h_last (encoder's final publish, buffer 0)
    float hprev[2];
    {
        unsigned pk0 = ld_c_u32(h_bf + bb * 1024 + j0 + jp * 2);
        WAIT_COHERENT();
        hprev[0] = lo2f(pk0);
        hprev[1] = hi2f(pk0);
    }
    unsigned sn = 0;
    const bf16* encT[3] = {encT0, encT1, encT2};

    for (int t = 0; t < 63; ++t) {
        const int cur = t & 1;
        const bf16* hbuf = h_bf + cur * 32768;

        // ========== Phase A ==========
        // coherent h-frags for GRU (reused in B) + own-batch h
        bf16x8 af[2][4];
        #pragma unroll
        for (int bt = 0; bt < 2; bt++)
            #pragma unroll
            for (int kk = 0; kk < 4; kk++)
                af[bt][kk] = ld_cv16(hbuf + ((size_t)(bt * 16 + lrow) * 128 + kw * 16 + kq + kk * 4) * 8);
        unsigned uh = ld_c_u32(hbuf + b * 1024 + tid * 2);
        WAIT_COHERENT();
        hbl[tid * 2]     = lo2f(uh);
        hbl[tid * 2 + 1] = hi2f(uh);
        __syncthreads();

        // a[e=tid] = sum_k Wh[e][k] * h[b][k], Whp k-major (lanes contiguous in e)
        {
            const u32x4* wp = reinterpret_cast<const u32x4*>(Whp);
            float s = 0.f;
            #pragma unroll 4
            for (int k8 = 0; k8 < 128; ++k8) {
                u32x4 u = wp[k8 * 512 + tid];
                const float* hp = &hbl[k8 * 8];
                #pragma unroll
                for (int i = 0; i < 4; ++i) {
                    s += lo2f(u[i]) * hp[2 * i];
                    s += hi2f(u[i]) * hp[2 * i + 1];
                }
            }
            a_ls[tid] = s;
        }
        __syncthreads();

        // scores: wave kw handles s = kw*8..kw*8+7, lanes cover e (coalesced)
        #pragma unroll
        for (int si = 0; si < 8; ++si) {
            const int s = kw * 8 + si;
            u32x4 u = *reinterpret_cast<const u32x4*>(enc_pj + ((size_t)b * 64 + s) * 512 + lane * 8);
            float p = 0.f;
            #pragma unroll
            for (int i = 0; i < 4; ++i) {
                p += vr[2 * i]     * tanh_fast(lo2f(u[i]) + a_ls[lane * 8 + 2 * i]);
                p += vr[2 * i + 1] * tanh_fast(hi2f(u[i]) + a_ls[lane * 8 + 2 * i + 1]);
            }
            #pragma unroll
            for (int off = 32; off; off >>= 1) p += __shfl_xor(p, off);
            if (lane == 0) sc_s[s] = p;
        }
        __syncthreads();
        if (tid < 64) {
            float v = sc_s[tid], m = v;
            #pragma unroll
            for (int off = 32; off; off >>= 1) m = fmaxf(m, __shfl_xor(m, off));
            float e = __expf(v - m);
            float su = e;
            #pragma unroll
            for (int off = 32; off; off >>= 1) su += __shfl_xor(su, off);
            st_c_u32(w_g + b * 64 + tid, __float_as_uint(e / su));
        }
        gsync(bar, ++sn * 32);

        // ========== Phase B ==========
        f32x4 wld = ld_cv16f(w_g + tid * 4);
        const size_t xb = ((size_t)bb * 63 + t) * 3072 + j0 + jp * 2;
        float2 xg0 = *reinterpret_cast<const float2*>(X + xb);
        float2 xg1 = *reinterpret_cast<const float2*>(X + xb + 1024);
        float2 xg2 = *reinterpret_cast<const float2*>(X + xb + 2048);
        WAIT_COHERENT();
        *reinterpret_cast<f32x4*>(&w_s[tid * 4]) = wld;

        f32x4 acc[3][2][2];
        #pragma unroll
        for (int g = 0; g < 3; g++)
            #pragma unroll
            for (int jt = 0; jt < 2; jt++)
                #pragma unroll
                for (int bt = 0; bt < 2; bt++) acc[g][jt][bt] = f32x4{0, 0, 0, 0};
        #pragma unroll
        for (int kk = 0; kk < 4; kk++)
            #pragma unroll
            for (int g = 0; g < 3; g++)
                #pragma unroll
                for (int jt = 0; jt < 2; jt++) {
                    acc[g][jt][0] = MFMA(af[0][kk], wB[g][jt][kk], acc[g][jt][0]);
                    acc[g][jt][1] = MFMA(af[1][kk], wB[g][jt][kk], acc[g][jt][1]);
                }
        #pragma unroll
        for (int g = 0; g < 3; g++)
            #pragma unroll
            for (int jt = 0; jt < 2; jt++)
                #pragma unroll
                for (int bt = 0; bt < 2; bt++)
                    #pragma unroll
                    for (int r = 0; r < 4; r++)
                        part[kw][g][bt * 16 + kq * 4 + r][jt * 16 + lrow] = acc[g][jt][bt][r];
        __syncthreads();

        // ctx-dot: c[g][o] = sum_s w[bb,s] * encT[g][bb*64+s][j0+jp*2+o]
        float c0[3] = {0, 0, 0}, c1[3] = {0, 0, 0};
        #pragma unroll
        for (int g = 0; g < 3; g++) {
            const bf16* base = encT[g] + (size_t)bb * 64 * 1024 + j0 + jp * 2;
            #pragma unroll 8
            for (int s = 0; s < 64; ++s) {
                unsigned u = *reinterpret_cast<const unsigned*>(base + (size_t)s * 1024);
                float w = w_s[bb * 64 + s];
                c0[g] += lo2f(u) * w;
                c1[g] += hi2f(u) * w;
            }
        }

        float h2o[2];
        #pragma unroll
        for (int o = 0; o < 2; ++o) {
            const int jc = jp * 2 + o;
            float g0 = 0.f, g1 = 0.f, g2 = 0.f;
            #pragma unroll
            for (int ww = 0; ww < 8; ww++) {
                g0 += part[ww][0][bb][jc];
                g1 += part[ww][1][bb][jc];
                g2 += part[ww][2][bb][jc];
            }
            float cc0 = o ? c1[0] : c0[0];
            float cc1 = o ? c1[1] : c0[1];
            float cc2 = o ? c1[2] : c0[2];
            float x0 = o ? xg0.y : xg0.x;
            float x1 = o ? xg1.y : xg1.x;
            float x2 = o ? xg2.y : xg2.x;
            float rr = sigm(x0 + cc0 + g0 + bh[0][o]);
            float zz = sigm(x1 + cc1 + g1 + bh[1][o]);
            float nn = tanh_fast(x2 + cc2 + rr * (g2 + bh[2][o]));
            h2o[o] = (1.f - zz) * nn + zz * hprev[o];
            hprev[o] = h2o[o];
        }
        unsigned pk = (unsigned)b2u(f2b(h2o[0])) | ((unsigned)b2u(f2b(h2o[1])) << 16);
        st_c_u32(h_bf + (cur ^ 1) * 32768 + bb * 1024 + j0 + jp * 2, pk);
        *reinterpret_cast<unsigned*>(Hall + ((size_t)bb * 63 + t) * 1024 + j0 + jp * 2) = pk;

        if (t < 62) gsync(bar, ++sn * 32);
    }
}

// ---------------------------------------------------------------------------
__global__ void init_k(bf16* __restrict__ h0, bf16* __restrict__ hall_pad,
                       int* __restrict__ idx_dec,
                       const int* __restrict__ tgt, unsigned* __restrict__ bar)
{
    const int i = blockIdx.x * blockDim.x + threadIdx.x;
    if (i < 64) bar[i] = 0u;
    if (i < 32768) {
        h0[i] = __float2bfloat16(0.f);
        hall_pad[i] = __float2bfloat16(0.f);
    }
    if (i < 2048) {
        int v = 0;
        if (i < 2016) { int bq = i / 63; int tq = i - bq * 63; v = tgt[bq * 64 + tq]; }
        idx_dec[i] = v;
    }
}

// ---------------------------------------------------------------------------
extern "C" void kernel_launch(void* const* d_in, const int* in_sizes, int n_in,
                              void* d_out, int out_size, void* d_ws, size_t ws_size,
                              hipStream_t stream)
{
    const int*   src       = (const int*)d_in[0];
    const int*   tgt       = (const int*)d_in[1];
    const float* src_embed = (const float*)d_in[2];
    const float* tgt_embed = (const float*)d_in[3];
    const float* enc_Wih   = (const float*)d_in[4];
    const float* enc_Whh   = (const float*)d_in[5];
    const float* enc_bih   = (const float*)d_in[6];
    const float* enc_bhh   = (const float*)d_in[7];
    const float* dec_Wih   = (const float*)d_in[8];
    const float* dec_Whh   = (const float*)d_in[9];
    const float* dec_bih   = (const float*)d_in[10];
    const float* dec_bhh   = (const float*)d_in[11];
    const float* attn_W    = (const float*)d_in[12];
    const float* attn_b    = (const float*)d_in[13];
    const float* v_w       = (const float*)d_in[14];
    const float* fc_W      = (const float*)d_in[15];
    const float* fc_b      = (const float*)d_in[16];

    char* w = (char*)d_ws;
    unsigned* bar      = (unsigned*)(w);             // [64]
    float* X_enc       = (float*)(w + 256);          // [2048][3072] f32
    float* X_dec       = (float*)(w + 25166080);     // [2048][3072] f32
    bf16*  enc_bf      = (bf16*) (w + 50331904);     // [2048][1024]
    bf16*  enc_pj_bf   = (bf16*) (w + 54526208);     // [2048][512]
    bf16*  H_all       = (bf16*) (w + 56623360);     // [2048][1024]
    bf16*  h_bf        = (bf16*) (w + 60817664);     // 2 x [32][1024]
    float* w_g         = (float*)(w + 60948736);     // [32][64]
    int*   idx_dec     = (int*)  (w + 61022464);     // [2048]
    bf16*  enc_Whh_bf  = (bf16*) (w + 61030656);     // [3072][1024]
    bf16*  dec_Whh_bf  = (bf16*) (w + 67322112);     // [3072][1024]
    bf16*  Whp         = (bf16*) (w + 73613568);     // [128][512][8]
    bf16*  encT0       = (bf16*) (w + 74662144);     // [2048][1024]
    bf16*  encT1       = (bf16*) (w + 78856448);     // [2048][1024]
    bf16*  encT2       = (bf16*) (w + 83050752);     // [2048][1024]
    bf16*  fc_W_bf     = (bf16*) (w + 87245056);     // [32000][1024]
    // total: 152,781,056 bytes

    init_k<<<128, 256, 0, stream>>>(h_bf, H_all + 2016 * 1024, idx_dec, tgt, bar);
    cvt_f32_bf16<<<3072, 256, 0, stream>>>(enc_Whh, enc_Whh_bf, 3145728);
    cvt_f32_bf16<<<3072, 256, 0, stream>>>(dec_Whh, dec_Whh_bf, 3145728);
    cvt_f32_bf16<<<32000, 256, 0, stream>>>(fc_W, fc_W_bf, 32768000);
    cvt_whp<<<256, 256, 0, stream>>>(attn_W, Whp);

    // X_enc = gather(src_embed, src) @ enc_Wih^T + enc_bih
    gemm_bt<float, float, float, true, true><<<dim3(24, 16), 256, 0, stream>>>(
        src_embed, src, 512, enc_Wih, 512, 0, enc_bih, X_enc, 3072, 1, 2048, 512);
    // X_dec = gather(tgt_embed, tgt[:, :-1]) @ dec_Wih[:, :512]^T + dec_bih
    gemm_bt<float, float, float, true, true><<<dim3(24, 16), 256, 0, stream>>>(
        tgt_embed, idx_dec, 512, dec_Wih, 1536, 0, dec_bih, X_dec, 3072, 1, 2048, 512);

    // encoder: persistent
    enc_persist<<<32, 512, 0, stream>>>(h_bf, X_enc, enc_Whh_bf, enc_bhh, enc_bf, bar);

    // enc_proj(bf16) = enc @ We^T + attn_b
    gemm_bt<bf16, float, bf16, false, true><<<dim3(4, 16), 256, 0, stream>>>(
        enc_bf, nullptr, 1024, attn_W, 2048, 1024, attn_b, enc_pj_bf, 512, 1, 2048, 1024);

    // encT[g][m][j] = enc @ dec_Wih[g-gate rows, 512:]^T   (j contiguous)
    gemm_bt<bf16, float, bf16, false, false><<<dim3(8, 16), 256, 0, stream>>>(
        enc_bf, nullptr, 1024, dec_Wih + (size_t)0 * 1024 * 1536, 1536, 512, nullptr, encT0, 1024, 1, 2048, 1024);
    gemm_bt<bf16, float, bf16, false, false><<<dim3(8, 16), 256, 0, stream>>>(
        enc_bf, nullptr, 1024, dec_Wih + (size_t)1 * 1024 * 1536, 1536, 512, nullptr, encT1, 1024, 1, 2048, 1024);
    gemm_bt<bf16, float, bf16, false, false><<<dim3(8, 16), 256, 0, stream>>>(
        enc_bf, nullptr, 1024, dec_Wih + (size_t)2 * 1024 * 1536, 1536, 512, nullptr, encT2, 1024, 1, 2048, 1024);

    // decoder: persistent (2 barriers/step)
    dec_persist<<<32, 512, 0, stream>>>(h_bf, X_dec, dec_Whh_bf, dec_bhh,
                                        encT0, encT1, encT2,
                                        H_all, Whp, enc_pj_bf, v_w,
                                        w_g, bar + 32);

    // logits = H_all @ fc_W_bf^T + fc_b -> d_out (f32)
    gemm_fc<<<4096, 256, 0, stream>>>(H_all, fc_W_bf, fc_b, (float*)d_out);
}

// Round 12
// 3071.437 us; speedup vs baseline: 2.0128x; 2.0128x over previous
//
#include <hip/hip_runtime.h>
#include <hip/hip_bf16.h>

typedef __hip_bfloat16 bf16;
typedef __attribute__((ext_vector_type(8))) __bf16 bf16x8;
typedef __attribute__((ext_vector_type(4))) float f32x4;
typedef __attribute__((ext_vector_type(4))) unsigned int u32x4;

#define DEVI __device__ __forceinline__

DEVI float sigm(float x) { return 1.f / (1.f + __expf(-x)); }
DEVI float tanh_fast(float x) { float e = __expf(2.f * x); return 1.f - 2.f / (e + 1.f); }
DEVI float lo2f(unsigned u) { return __uint_as_float(u << 16); }
DEVI float hi2f(unsigned u) { return __uint_as_float(u & 0xffff0000u); }

DEVI __bf16 f2b(float f) {               // RNE f32->bf16
    unsigned u = __float_as_uint(f);
    u = u + 0x7FFFu + ((u >> 16) & 1u);
    unsigned short s = (unsigned short)(u >> 16);
    __bf16 b;
    __builtin_memcpy(&b, &s, 2);
    return b;
}
DEVI unsigned short b2u(__bf16 b) { unsigned short s; __builtin_memcpy(&s, &b, 2); return s; }

DEVI f32x4 MFMA(bf16x8 a, bf16x8 b, f32x4 c) {
    return __builtin_amdgcn_mfma_f32_16x16x32_bf16(a, b, c, 0, 0, 0);
}

DEVI bf16x8 load8(const bf16* p) { return *reinterpret_cast<const bf16x8*>(p); }
DEVI bf16x8 load8(const float* p) {
    float4 a = *reinterpret_cast<const float4*>(p);
    float4 b = *reinterpret_cast<const float4*>(p + 4);
    bf16x8 r;
    r[0] = f2b(a.x); r[1] = f2b(a.y); r[2] = f2b(a.z); r[3] = f2b(a.w);
    r[4] = f2b(b.x); r[5] = f2b(b.y); r[6] = f2b(b.z); r[7] = f2b(b.w);
    return r;
}

DEVI void storeOut(float* p, float v) { *p = v; }
DEVI void storeOut(bf16* p, float v) { *p = __float2bfloat16(v); }

// ---- coherent (cache-bypassing) memory ops via asm sc0 sc1 -----------------
#define WAIT_COHERENT() do { \
    asm volatile("s_waitcnt vmcnt(0)" ::: "memory"); \
    __builtin_amdgcn_sched_barrier(0); } while (0)

DEVI bf16x8 ld_cv16(const bf16* p) {
    u32x4 r;
    asm volatile("global_load_dwordx4 %0, %1, off sc0 sc1"
                 : "=v"(r) : "v"(p) : "memory");
    bf16x8 out;
    __builtin_memcpy(&out, &r, 16);
    return out;
}
DEVI f32x4 ld_cv16f(const float* p) {
    f32x4 r;
    asm volatile("global_load_dwordx4 %0, %1, off sc0 sc1"
                 : "=v"(r) : "v"(p) : "memory");
    return r;
}
DEVI unsigned ld_c_u32(const void* p) {
    unsigned r;
    asm volatile("global_load_dword %0, %1, off sc0 sc1"
                 : "=v"(r) : "v"(p) : "memory");
    return r;
}
DEVI void st_c_u32(void* p, unsigned v) {
    asm volatile("global_store_dword %0, %1, off sc0 sc1"
                 :: "v"(p), "v"(v) : "memory");
}

// ---------------------------------------------------------------------------
// Grid barrier (PROVEN r7-r10): drain own vmem, then atomic counter add +
// atomic RMW poll. Atomics execute at the coherence point — this is the only
// sync primitive verified on this hardware path (plain-store flag poll hung).
// ---------------------------------------------------------------------------
DEVI void gsync(unsigned* bar, unsigned target) {
    asm volatile("s_waitcnt vmcnt(0)" ::: "memory");
    __syncthreads();
    if (threadIdx.x == 0) {
        __hip_atomic_fetch_add(bar, 1u, __ATOMIC_RELAXED, __HIP_MEMORY_SCOPE_AGENT);
        while (atomicAdd(bar, 0u) < target) __builtin_amdgcn_s_sleep(8);
    }
    asm volatile("" ::: "memory");
    __syncthreads();
}

// ---------------------------------------------------------------------------
// Generic MFMA GEMM: C[m*crs + n*ccs] = sum_k A[m,k]*B[n,k] (+bias[n]).
// ---------------------------------------------------------------------------
template<typename AT, typename BT, typename OT, bool GATHER, bool HASB>
__global__ __launch_bounds__(256)
void gemm_bt(const AT* __restrict__ A, const int* __restrict__ Aidx, int lda,
             const BT* __restrict__ B, int ldb, int boff,
             const float* __restrict__ bias,
             OT* __restrict__ C, long crs, long ccs,
             int M_real, int K)
{
    __shared__ __attribute__((aligned(16))) bf16 As[128 * 32];
    __shared__ __attribute__((aligned(16))) bf16 Bs[128 * 32];
    const int tid = threadIdx.x;
    const int lane = tid & 63;
    const int w = tid >> 6;
    const int wr = w >> 1, wc = w & 1;
    const int bm = blockIdx.y * 128;
    const int bn = blockIdx.x * 128;

    const int l16_0 = (2 * w + 0) * 64 + lane;
    const int l16_1 = (2 * w + 1) * 64 + lane;
    const int row0 = l16_0 >> 2, c0 = l16_0 & 3;
    const int row1 = l16_1 >> 2, c1 = l16_1 & 3;

    long arow0 = GATHER ? (long)Aidx[bm + row0] : (long)(bm + row0);
    long arow1 = GATHER ? (long)Aidx[bm + row1] : (long)(bm + row1);
    const AT* agp0 = A + arow0 * lda + c0 * 8;
    const AT* agp1 = A + arow1 * lda + c1 * 8;
    const BT* bgp0 = B + (long)(bn + row0) * ldb + boff + c0 * 8;
    const BT* bgp1 = B + (long)(bn + row1) * ldb + boff + c1 * 8;

    f32x4 acc[4][4];
    #pragma unroll
    for (int i = 0; i < 4; i++)
        #pragma unroll
        for (int j = 0; j < 4; j++) acc[i][j] = f32x4{0.f, 0.f, 0.f, 0.f};

    const bf16x8* Asv = reinterpret_cast<const bf16x8*>(As);
    const bf16x8* Bsv = reinterpret_cast<const bf16x8*>(Bs);
    bf16x8* AsW = reinterpret_cast<bf16x8*>(As);
    bf16x8* BsW = reinterpret_cast<bf16x8*>(Bs);
    const int kq = lane >> 4;
    const int lrow = lane & 15;

    bf16x8 ra0 = load8(agp0);
    bf16x8 ra1 = load8(agp1);
    bf16x8 rb0 = load8(bgp0);
    bf16x8 rb1 = load8(bgp1);

    for (int k0 = 0; k0 < K; k0 += 32) {
        __syncthreads();
        AsW[l16_0] = ra0; AsW[l16_1] = ra1;
        BsW[l16_0] = rb0; BsW[l16_1] = rb1;
        __syncthreads();

        const int kn = k0 + 32;
        if (kn < K) {
            ra0 = load8(agp0 + kn);
            ra1 = load8(agp1 + kn);
            rb0 = load8(bgp0 + kn);
            rb1 = load8(bgp1 + kn);
        }

        bf16x8 af[4], bfr[4];
        #pragma unroll
        for (int mt = 0; mt < 4; mt++) af[mt] = Asv[(wr * 64 + mt * 16 + lrow) * 4 + kq];
        #pragma unroll
        for (int nt = 0; nt < 4; nt++) bfr[nt] = Bsv[(wc * 64 + nt * 16 + lrow) * 4 + kq];
        #pragma unroll
        for (int mt = 0; mt < 4; mt++)
            #pragma unroll
            for (int nt = 0; nt < 4; nt++)
                acc[mt][nt] = MFMA(af[mt], bfr[nt], acc[mt][nt]);
    }

    const int rbase = kq * 4;
    #pragma unroll
    for (int nt = 0; nt < 4; nt++) {
        const int col = bn + wc * 64 + nt * 16 + lrow;
        float bv = 0.f;
        if (HASB) bv = bias[col];
        #pragma unroll
        for (int mt = 0; mt < 4; mt++) {
            const int rw = bm + wr * 64 + mt * 16 + rbase;
            #pragma unroll
            for (int r = 0; r < 4; r++) {
                const int row = rw + r;
                if (row < M_real) storeOut(&C[(long)row * crs + (long)col * ccs], acc[mt][nt][r] + bv);
            }
        }
    }
}

// ---------------------------------------------------------------------------
// FC GEMM: logits = H_all @ B^T + fc_b, XCD panel mapping. B templated
// (f32 source, inline-converted during reg staging -> no cvt pass needed).
// ---------------------------------------------------------------------------
template<typename BT>
__global__ __launch_bounds__(256)
void gemm_fc(const bf16* __restrict__ A, const BT* __restrict__ B,
             const float* __restrict__ bias, float* __restrict__ C)
{
    __shared__ __attribute__((aligned(16))) bf16 As[8192];
    __shared__ __attribute__((aligned(16))) bf16 Bs[8192];
    const int tid = threadIdx.x;
    const int bid = blockIdx.x;
    const int xcd = bid & 7;
    const int ii = bid >> 3;
    const int p = xcd + 8 * (ii >> 4);
    const int m = ii & 15;
    if (p >= 250) return;
    const int bm = m * 128, bn = p * 128;

    const int lane = tid & 63, w = tid >> 6, wr = w >> 1, wc = w & 1;
    const int kq = lane >> 4, lrow = lane & 15;

    int rowc[4], c8c[4];
    const bf16* gA[4];
    const BT* gB[4];
    #pragma unroll
    for (int c = 0; c < 4; c++) {
        int q = c * 256 + tid;
        rowc[c] = q >> 3; c8c[c] = q & 7;
        gA[c] = A + (long)(bm + rowc[c]) * 1024 + c8c[c] * 8;
        gB[c] = B + (long)(bn + rowc[c]) * 1024 + c8c[c] * 8;
    }

    f32x4 acc[4][4];
    #pragma unroll
    for (int i = 0; i < 4; i++)
        #pragma unroll
        for (int j = 0; j < 4; j++) acc[i][j] = f32x4{0.f, 0.f, 0.f, 0.f};

    bf16x8* AsW = reinterpret_cast<bf16x8*>(As);
    bf16x8* BsW = reinterpret_cast<bf16x8*>(Bs);
    const bf16x8* Asv = reinterpret_cast<const bf16x8*>(As);
    const bf16x8* Bsv = reinterpret_cast<const bf16x8*>(Bs);

    bf16x8 ra[4], rb[4];
    #pragma unroll
    for (int c = 0; c < 4; c++) { ra[c] = load8(gA[c]); rb[c] = load8(gB[c]); }

    for (int kt = 0; kt < 16; ++kt) {
        __syncthreads();
        #pragma unroll
        for (int c = 0; c < 4; c++) {
            AsW[c8c[c] * 128 + rowc[c]] = ra[c];
            BsW[c8c[c] * 128 + rowc[c]] = rb[c];
        }
        __syncthreads();
        if (kt < 15) {
            const int ko = (kt + 1) * 64;
            #pragma unroll
            for (int c = 0; c < 4; c++) { ra[c] = load8(gA[c] + ko); rb[c] = load8(gB[c] + ko); }
        }
        #pragma unroll
        for (int h = 0; h < 2; ++h) {
            bf16x8 af[4], bfr[4];
            #pragma unroll
            for (int mt = 0; mt < 4; mt++) af[mt] = Asv[(h * 4 + kq) * 128 + wr * 64 + mt * 16 + lrow];
            #pragma unroll
            for (int nt = 0; nt < 4; nt++) bfr[nt] = Bsv[(h * 4 + kq) * 128 + wc * 64 + nt * 16 + lrow];
            #pragma unroll
            for (int mt = 0; mt < 4; mt++)
                #pragma unroll
                for (int nt = 0; nt < 4; nt++)
                    acc[mt][nt] = MFMA(af[mt], bfr[nt], acc[mt][nt]);
        }
    }

    const int rbase = kq * 4;
    #pragma unroll
    for (int nt = 0; nt < 4; nt++) {
        const int col = bn + wc * 64 + nt * 16 + lrow;
        const float bv = bias[col];
        #pragma unroll
        for (int mt = 0; mt < 4; mt++) {
            const int rw = bm + wr * 64 + mt * 16 + rbase;
            #pragma unroll
            for (int r = 0; r < 4; r++) {
                const int row = rw + r;
                if (row < 2016) C[(long)row * 32000 + col] = acc[mt][nt][r] + bv;
            }
        }
    }
}

// ---------------------------------------------------------------------------
__global__ __launch_bounds__(256)
void cvt_f32_bf16(const float* __restrict__ in, bf16* __restrict__ out, int n)
{
    int i = (blockIdx.x * blockDim.x + threadIdx.x) * 4;
    if (i < n) {
        float4 v = *reinterpret_cast<const float4*>(in + i);
        ushort4 o;
        o.x = b2u(f2b(v.x)); o.y = b2u(f2b(v.y));
        o.z = b2u(f2b(v.z)); o.w = b2u(f2b(v.w));
        *reinterpret_cast<ushort4*>(out + i) = o;
    }
}

// Wh_bf[e][k] = bf16(attn_W[e][k]) for k<1024 (attn_W is [512][2048])
__global__ __launch_bounds__(256)
void cvt_wh(const float* __restrict__ in, bf16* __restrict__ out)
{
    int i = (blockIdx.x * blockDim.x + threadIdx.x) * 4;
    if (i < 524288) {
        int e = i >> 10, k = i & 1023;
        float4 v = *reinterpret_cast<const float4*>(in + (size_t)e * 2048 + k);
        ushort4 o;
        o.x = b2u(f2b(v.x)); o.y = b2u(f2b(v.y));
        o.z = b2u(f2b(v.z)); o.w = b2u(f2b(v.w));
        *reinterpret_cast<ushort4*>(out + i) = o;
    }
}

// ---------------------------------------------------------------------------
// Persistent encoder (r9-proven structure, atomic barrier).
// ---------------------------------------------------------------------------
__global__ __launch_bounds__(512, 1)
void enc_persist(bf16* __restrict__ h_bf,
                 const float* __restrict__ X,
                 const bf16* __restrict__ Whh, const float* __restrict__ bhh,
                 bf16* __restrict__ enc_out,
                 unsigned* __restrict__ bar)
{
    __shared__ float part[8][3][32][33];
    const int tid = threadIdx.x;
    const int lane = tid & 63;
    const int kw = tid >> 6;
    const int lrow = lane & 15;
    const int kq = lane >> 4;
    const int j0 = blockIdx.x * 32;

    const bf16x8* wv = reinterpret_cast<const bf16x8*>(Whh);
    bf16x8 wB[3][2][4];
    #pragma unroll
    for (int g = 0; g < 3; g++)
        #pragma unroll
        for (int jt = 0; jt < 2; jt++)
            #pragma unroll
            for (int kk = 0; kk < 4; kk++)
                wB[g][jt][kk] = wv[(size_t)(g * 1024 + j0 + jt * 16 + lrow) * 128 + kw * 16 + kq + kk * 4];

    const int bb = tid >> 4;
    const int jp = tid & 15;
    float bh[3][2];
    #pragma unroll
    for (int g = 0; g < 3; g++) {
        bh[g][0] = bhh[g * 1024 + j0 + jp * 2];
        bh[g][1] = bhh[g * 1024 + j0 + jp * 2 + 1];
    }
    float hprev[2] = {0.f, 0.f};
    unsigned sn = 0;

    for (int t = 0; t < 64; ++t) {
        const int cur = t & 1;
        const bf16* hbuf = h_bf + cur * 32768;

        bf16x8 af[2][4];
        #pragma unroll
        for (int bt = 0; bt < 2; bt++)
            #pragma unroll
            for (int kk = 0; kk < 4; kk++)
                af[bt][kk] = ld_cv16(hbuf + ((size_t)(bt * 16 + lrow) * 128 + kw * 16 + kq + kk * 4) * 8);

        const size_t xb = ((size_t)bb * 64 + t) * 3072 + j0 + jp * 2;
        float2 xg0 = *reinterpret_cast<const float2*>(X + xb);
        float2 xg1 = *reinterpret_cast<const float2*>(X + xb + 1024);
        float2 xg2 = *reinterpret_cast<const float2*>(X + xb + 2048);
        WAIT_COHERENT();

        f32x4 acc[3][2][2];
        #pragma unroll
        for (int g = 0; g < 3; g++)
            #pragma unroll
            for (int jt = 0; jt < 2; jt++)
                #pragma unroll
                for (int bt = 0; bt < 2; bt++) acc[g][jt][bt] = f32x4{0, 0, 0, 0};
        #pragma unroll
        for (int kk = 0; kk < 4; kk++)
            #pragma unroll
            for (int g = 0; g < 3; g++)
                #pragma unroll
                for (int jt = 0; jt < 2; jt++) {
                    acc[g][jt][0] = MFMA(af[0][kk], wB[g][jt][kk], acc[g][jt][0]);
                    acc[g][jt][1] = MFMA(af[1][kk], wB[g][jt][kk], acc[g][jt][1]);
                }
        #pragma unroll
        for (int g = 0; g < 3; g++)
            #pragma unroll
            for (int jt = 0; jt < 2; jt++)
                #pragma unroll
                for (int bt = 0; bt < 2; bt++)
                    #pragma unroll
                    for (int r = 0; r < 4; r++)
                        part[kw][g][bt * 16 + kq * 4 + r][jt * 16 + lrow] = acc[g][jt][bt][r];
        __syncthreads();

        float h2o[2];
        #pragma unroll
        for (int o = 0; o < 2; ++o) {
            const int jc = jp * 2 + o;
            float s0 = 0.f, s1 = 0.f, s2 = 0.f;
            #pragma unroll
            for (int ww = 0; ww < 8; ww++) {
                s0 += part[ww][0][bb][jc];
                s1 += part[ww][1][bb][jc];
                s2 += part[ww][2][bb][jc];
            }
            float x0 = o ? xg0.y : xg0.x;
            float x1 = o ? xg1.y : xg1.x;
            float x2 = o ? xg2.y : xg2.x;
            float rr = sigm(x0 + s0 + bh[0][o]);
            float zz = sigm(x1 + s1 + bh[1][o]);
            float nn = tanh_fast(x2 + rr * (s2 + bh[2][o]));
            h2o[o] = (1.f - zz) * nn + zz * hprev[o];
            hprev[o] = h2o[o];
        }
        unsigned pk = (unsigned)b2u(f2b(h2o[0])) | ((unsigned)b2u(f2b(h2o[1])) << 16);
        st_c_u32(h_bf + (cur ^ 1) * 32768 + bb * 1024 + j0 + jp * 2, pk);
        *reinterpret_cast<unsigned*>(enc_out + ((size_t)bb * 64 + t) * 1024 + j0 + jp * 2) = pk;

        if (t < 63) gsync(bar, ++sn * 32);
    }
}

// ---------------------------------------------------------------------------
// Persistent decoder (r9 structure, atomic barrier, transposed a_gT exchange).
//  P1: coherent h-frags (reused in P3); a[e-slice, all b] via MFMA (Wh frags
//      hoisted); publish a_gT[b][e] (scattered stores -> coalesced reads).
//  P2: gather a_gT[b][:] coalesced; coalesced scores; softmax; publish w[b,:].
//  P3: GRU MFMA + ctx-dot on per-gate [m][j] encT; pointwise; publish h.
// ---------------------------------------------------------------------------
__global__ __launch_bounds__(512, 1)
void dec_persist(bf16* __restrict__ h_bf,
                 const float* __restrict__ X,
                 const bf16* __restrict__ Whh, const float* __restrict__ bhh,
                 const bf16* __restrict__ encT0,   // [2048 m][1024 j] per gate
                 const bf16* __restrict__ encT1,
                 const bf16* __restrict__ encT2,
                 bf16* __restrict__ Hall,
                 const bf16* __restrict__ Wh_bf,   // [512][1024] bf16
                 const bf16* __restrict__ enc_pj,  // [2048 m][512 e] bf16
                 const float* __restrict__ v_w,
                 float* __restrict__ a_gT,         // [32 b][512 e] f32
                 float* __restrict__ w_g,          // [32 b][64 s] f32
                 unsigned* __restrict__ bar)
{
    __shared__ float part[8][3][32][33];      // ~101 KB
    __shared__ float apart[8][16][32];        // 16 KB
    __shared__ __attribute__((aligned(16))) float a_ls[512];
    __shared__ __attribute__((aligned(16))) float w_s[2048];   // [32][64]
    __shared__ float sc_s[64];

    const int tid = threadIdx.x;
    const int lane = tid & 63;
    const int kw = tid >> 6;
    const int lrow = lane & 15;
    const int kq = lane >> 4;
    const int j0 = blockIdx.x * 32;
    const int e0 = blockIdx.x * 16;           // a e-slice
    const int b = blockIdx.x;                 // attention batch

    // hoisted Whh fragments (96 VGPR)
    const bf16x8* wv = reinterpret_cast<const bf16x8*>(Whh);
    bf16x8 wB[3][2][4];
    #pragma unroll
    for (int g = 0; g < 3; g++)
        #pragma unroll
        for (int jt = 0; jt < 2; jt++)
            #pragma unroll
            for (int kk = 0; kk < 4; kk++)
                wB[g][jt][kk] = wv[(size_t)(g * 1024 + j0 + jt * 16 + lrow) * 128 + kw * 16 + kq + kk * 4];

    // hoisted Wh A-fragments for a-MFMA (16 VGPR)
    const bf16x8* whv = reinterpret_cast<const bf16x8*>(Wh_bf);
    bf16x8 whA[4];
    #pragma unroll
    for (int kk = 0; kk < 4; kk++)
        whA[kk] = whv[(size_t)(e0 + lrow) * 128 + kw * 16 + kq + kk * 4];

    // hoisted v_w chunk: e = lane*8 + ii
    float vr[8];
    #pragma unroll
    for (int ii = 0; ii < 8; ii++) vr[ii] = v_w[lane * 8 + ii];

    const int bb = tid >> 4;
    const int jp = tid & 15;
    float bh[3][2];
    #pragma unroll
    for (int g = 0; g < 3; g++) {
        bh[g][0] = bhh[g * 1024 + j0 + jp * 2];
        bh[g][1] = bhh[g * 1024 + j0 + jp * 2 + 1];
    }

    // seed hprev from h_last (encoder's final publish, buffer 0)
    float hprev[2];
    {
        unsigned pk0 = ld_c_u32(h_bf + bb * 1024 + j0 + jp * 2);
        WAIT_COHERENT();
        hprev[0] = lo2f(pk0);
        hprev[1] = hi2f(pk0);
    }
    unsigned sn = 0;
    const bf16* encT[3] = {encT0, encT1, encT2};

    for (int t = 0; t < 63; ++t) {
        const int cur = t & 1;
        const bf16* hbuf = h_bf + cur * 32768;

        // ========== P1: h-frags (coherent) + a-MFMA + publish a-slice ======
        bf16x8 af[2][4];
        #pragma unroll
        for (int bt = 0; bt < 2; bt++)
            #pragma unroll
            for (int kk = 0; kk < 4; kk++)
                af[bt][kk] = ld_cv16(hbuf + ((size_t)(bt * 16 + lrow) * 128 + kw * 16 + kq + kk * 4) * 8);
        WAIT_COHERENT();

        {
            f32x4 aa[2] = {f32x4{0,0,0,0}, f32x4{0,0,0,0}};
            #pragma unroll
            for (int kk = 0; kk < 4; kk++) {
                aa[0] = MFMA(whA[kk], af[0][kk], aa[0]);
                aa[1] = MFMA(whA[kk], af[1][kk], aa[1]);
            }
            #pragma unroll
            for (int bt = 0; bt < 2; bt++)
                #pragma unroll
                for (int r = 0; r < 4; r++)
                    apart[kw][kq * 4 + r][bt * 16 + lrow] = aa[bt][r];
        }
        __syncthreads();
        {
            const int e = tid >> 5, bq = tid & 31;
            float s = 0.f;
            #pragma unroll
            for (int ww = 0; ww < 8; ww++) s += apart[ww][e][bq];
            // transposed publish: a_gT[bq][e0+e] (stores scatter; reads coalesce)
            st_c_u32(a_gT + (size_t)bq * 512 + e0 + e, __float_as_uint(s));
        }
        gsync(bar, ++sn * 32);

        // ========== P2: coalesced a-gather + scores + softmax + publish w ===
        {
            unsigned av = ld_c_u32(a_gT + (size_t)b * 512 + tid);   // coalesced
            WAIT_COHERENT();
            a_ls[tid] = __uint_as_float(av);
        }
        __syncthreads();
        #pragma unroll
        for (int si = 0; si < 8; ++si) {
            const int s = kw * 8 + si;
            u32x4 u = *reinterpret_cast<const u32x4*>(enc_pj + ((size_t)b * 64 + s) * 512 + lane * 8);
            float p = 0.f;
            #pragma unroll
            for (int i = 0; i < 4; ++i) {
                p += vr[2 * i]     * tanh_fast(lo2f(u[i]) + a_ls[lane * 8 + 2 * i]);
                p += vr[2 * i + 1] * tanh_fast(hi2f(u[i]) + a_ls[lane * 8 + 2 * i + 1]);
            }
            #pragma unroll
            for (int off = 32; off; off >>= 1) p += __shfl_xor(p, off);
            if (lane == 0) sc_s[s] = p;
        }
        __syncthreads();
        if (tid < 64) {
            float v = sc_s[tid], m = v;
            #pragma unroll
            for (int off = 32; off; off >>= 1) m = fmaxf(m, __shfl_xor(m, off));
            float e = __expf(v - m);
            float su = e;
            #pragma unroll
            for (int off = 32; off; off >>= 1) su += __shfl_xor(su, off);
            st_c_u32(w_g + b * 64 + tid, __float_as_uint(e / su));
        }
        gsync(bar, ++sn * 32);

        // ========== P3: GRU (af reused) + ctx-dot + pointwise + publish h ===
        f32x4 wld = ld_cv16f(w_g + tid * 4);
        const size_t xb = ((size_t)bb * 63 + t) * 3072 + j0 + jp * 2;
        float2 xg0 = *reinterpret_cast<const float2*>(X + xb);
        float2 xg1 = *reinterpret_cast<const float2*>(X + xb + 1024);
        float2 xg2 = *reinterpret_cast<const float2*>(X + xb + 2048);
        WAIT_COHERENT();
        *reinterpret_cast<f32x4*>(&w_s[tid * 4]) = wld;

        f32x4 acc[3][2][2];
        #pragma unroll
        for (int g = 0; g < 3; g++)
            #pragma unroll
            for (int jt = 0; jt < 2; jt++)
                #pragma unroll
                for (int bt = 0; bt < 2; bt++) acc[g][jt][bt] = f32x4{0, 0, 0, 0};
        #pragma unroll
        for (int kk = 0; kk < 4; kk++)
            #pragma unroll
            for (int g = 0; g < 3; g++)
                #pragma unroll
                for (int jt = 0; jt < 2; jt++) {
                    acc[g][jt][0] = MFMA(af[0][kk], wB[g][jt][kk], acc[g][jt][0]);
                    acc[g][jt][1] = MFMA(af[1][kk], wB[g][jt][kk], acc[g][jt][1]);
                }
        #pragma unroll
        for (int g = 0; g < 3; g++)
            #pragma unroll
            for (int jt = 0; jt < 2; jt++)
                #pragma unroll
                for (int bt = 0; bt < 2; bt++)
                    #pragma unroll
                    for (int r = 0; r < 4; r++)
                        part[kw][g][bt * 16 + kq * 4 + r][jt * 16 + lrow] = acc[g][jt][bt][r];
        __syncthreads();

        // ctx-dot: c[g][o] = sum_s w[bb,s] * encT[g][bb*64+s][j0+jp*2+o]
        float c0[3] = {0, 0, 0}, c1[3] = {0, 0, 0};
        #pragma unroll
        for (int g = 0; g < 3; g++) {
            const bf16* base = encT[g] + (size_t)bb * 64 * 1024 + j0 + jp * 2;
            #pragma unroll 8
            for (int s = 0; s < 64; ++s) {
                unsigned u = *reinterpret_cast<const unsigned*>(base + (size_t)s * 1024);
                float w = w_s[bb * 64 + s];
                c0[g] += lo2f(u) * w;
                c1[g] += hi2f(u) * w;
            }
        }

        float h2o[2];
        #pragma unroll
        for (int o = 0; o < 2; ++o) {
            const int jc = jp * 2 + o;
            float g0 = 0.f, g1 = 0.f, g2 = 0.f;
            #pragma unroll
            for (int ww = 0; ww < 8; ww++) {
                g0 += part[ww][0][bb][jc];
                g1 += part[ww][1][bb][jc];
                g2 += part[ww][2][bb][jc];
            }
            float cc0 = o ? c1[0] : c0[0];
            float cc1 = o ? c1[1] : c0[1];
            float cc2 = o ? c1[2] : c0[2];
            float x0 = o ? xg0.y : xg0.x;
            float x1 = o ? xg1.y : xg1.x;
            float x2 = o ? xg2.y : xg2.x;
            float rr = sigm(x0 + cc0 + g0 + bh[0][o]);
            float zz = sigm(x1 + cc1 + g1 + bh[1][o]);
            float nn = tanh_fast(x2 + cc2 + rr * (g2 + bh[2][o]));
            h2o[o] = (1.f - zz) * nn + zz * hprev[o];
            hprev[o] = h2o[o];
        }
        unsigned pk = (unsigned)b2u(f2b(h2o[0])) | ((unsigned)b2u(f2b(h2o[1])) << 16);
        st_c_u32(h_bf + (cur ^ 1) * 32768 + bb * 1024 + j0 + jp * 2, pk);
        *reinterpret_cast<unsigned*>(Hall + ((size_t)bb * 63 + t) * 1024 + j0 + jp * 2) = pk;

        if (t < 62) gsync(bar, ++sn * 32);
    }
}

// ---------------------------------------------------------------------------
__global__ void init_k(bf16* __restrict__ h0, bf16* __restrict__ hall_pad,
                       int* __restrict__ idx_dec,
                       const int* __restrict__ tgt, unsigned* __restrict__ bar)
{
    const int i = blockIdx.x * blockDim.x + threadIdx.x;
    if (i < 64) bar[i] = 0u;
    if (i < 32768) {
        h0[i] = __float2bfloat16(0.f);
        hall_pad[i] = __float2bfloat16(0.f);
    }
    if (i < 2048) {
        int v = 0;
        if (i < 2016) { int bq = i / 63; int tq = i - bq * 63; v = tgt[bq * 64 + tq]; }
        idx_dec[i] = v;
    }
}

// ---------------------------------------------------------------------------
extern "C" void kernel_launch(void* const* d_in, const int* in_sizes, int n_in,
                              void* d_out, int out_size, void* d_ws, size_t ws_size,
                              hipStream_t stream)
{
    const int*   src       = (const int*)d_in[0];
    const int*   tgt       = (const int*)d_in[1];
    const float* src_embed = (const float*)d_in[2];
    const float* tgt_embed = (const float*)d_in[3];
    const float* enc_Wih   = (const float*)d_in[4];
    const float* enc_Whh   = (const float*)d_in[5];
    const float* enc_bih   = (const float*)d_in[6];
    const float* enc_bhh   = (const float*)d_in[7];
    const float* dec_Wih   = (const float*)d_in[8];
    const float* dec_Whh   = (const float*)d_in[9];
    const float* dec_bih   = (const float*)d_in[10];
    const float* dec_bhh   = (const float*)d_in[11];
    const float* attn_W    = (const float*)d_in[12];
    const float* attn_b    = (const float*)d_in[13];
    const float* v_w       = (const float*)d_in[14];
    const float* fc_W      = (const float*)d_in[15];
    const float* fc_b      = (const float*)d_in[16];

    char* w = (char*)d_ws;
    unsigned* bar      = (unsigned*)(w);             // [64]
    float* X_enc       = (float*)(w + 256);          // [2048][3072] f32
    float* X_dec       = (float*)(w + 25166080);     // [2048][3072] f32
    bf16*  enc_bf      = (bf16*) (w + 50331904);     // [2048][1024]
    bf16*  enc_pj_bf   = (bf16*) (w + 54526208);     // [2048][512]
    bf16*  H_all       = (bf16*) (w + 56623360);     // [2048][1024]
    bf16*  h_bf        = (bf16*) (w + 60817664);     // 2 x [32][1024]
    float* w_g         = (float*)(w + 60948736);     // [32][64]
    float* a_gT        = (float*)(w + 60956928);     // [32][512]
    int*   idx_dec     = (int*)  (w + 61022464);     // [2048]
    bf16*  enc_Whh_bf  = (bf16*) (w + 61030656);     // [3072][1024]
    bf16*  dec_Whh_bf  = (bf16*) (w + 67322112);     // [3072][1024]
    bf16*  Wh_bf       = (bf16*) (w + 73613568);     // [512][1024]
    bf16*  encT0       = (bf16*) (w + 74662144);     // [2048][1024]
    bf16*  encT1       = (bf16*) (w + 78856448);     // [2048][1024]
    bf16*  encT2       = (bf16*) (w + 83050752);     // [2048][1024]
    // total: 87,245,056 bytes

    init_k<<<128, 256, 0, stream>>>(h_bf, H_all + 2016 * 1024, idx_dec, tgt, bar);
    cvt_f32_bf16<<<3072, 256, 0, stream>>>(enc_Whh, enc_Whh_bf, 3145728);
    cvt_f32_bf16<<<3072, 256, 0, stream>>>(dec_Whh, dec_Whh_bf, 3145728);
    cvt_wh<<<512, 256, 0, stream>>>(attn_W, Wh_bf);

    // X_enc = gather(src_embed, src) @ enc_Wih^T + enc_bih
    gemm_bt<float, float, float, true, true><<<dim3(24, 16), 256, 0, stream>>>(
        src_embed, src, 512, enc_Wih, 512, 0, enc_bih, X_enc, 3072, 1, 2048, 512);
    // X_dec = gather(tgt_embed, tgt[:, :-1]) @ dec_Wih[:, :512]^T + dec_bih
    gemm_bt<float, float, float, true, true><<<dim3(24, 16), 256, 0, stream>>>(
        tgt_embed, idx_dec, 512, dec_Wih, 1536, 0, dec_bih, X_dec, 3072, 1, 2048, 512);

    // encoder: persistent
    enc_persist<<<32, 512, 0, stream>>>(h_bf, X_enc, enc_Whh_bf, enc_bhh, enc_bf, bar);

    // enc_proj(bf16) = enc @ We^T + attn_b
    gemm_bt<bf16, float, bf16, false, true><<<dim3(4, 16), 256, 0, stream>>>(
        enc_bf, nullptr, 1024, attn_W, 2048, 1024, attn_b, enc_pj_bf, 512, 1, 2048, 1024);

    // encT[g][m][j] = enc @ dec_Wih[g-gate rows, 512:]^T   (j contiguous)
    gemm_bt<bf16, float, bf16, false, false><<<dim3(8, 16), 256, 0, stream>>>(
        enc_bf, nullptr, 1024, dec_Wih + (size_t)0 * 1024 * 1536, 1536, 512, nullptr, encT0, 1024, 1, 2048, 1024);
    gemm_bt<bf16, float, bf16, false, false><<<dim3(8, 16), 256, 0, stream>>>(
        enc_bf, nullptr, 1024, dec_Wih + (size_t)1 * 1024 * 1536, 1536, 512, nullptr, encT1, 1024, 1, 2048, 1024);
    gemm_bt<bf16, float, bf16, false, false><<<dim3(8, 16), 256, 0, stream>>>(
        enc_bf, nullptr, 1024, dec_Wih + (size_t)2 * 1024 * 1536, 1536, 512, nullptr, encT2, 1024, 1, 2048, 1024);

    // decoder: persistent (3 atomic barriers/step)
    dec_persist<<<32, 512, 0, stream>>>(h_bf, X_dec, dec_Whh_bf, dec_bhh,
                                        encT0, encT1, encT2,
                                        H_all, Wh_bf, enc_pj_bf, v_w,
                                        a_gT, w_g, bar + 32);

    // logits = H_all @ fc_W^T (f32 B, inline cvt) + fc_b -> d_out (f32)
    gemm_fc<float><<<4096, 256, 0, stream>>>(H_all, fc_W, fc_b, (float*)d_out);
}

// Round 13
// 3033.913 us; speedup vs baseline: 2.0376x; 1.0124x over previous
//
#include <hip/hip_runtime.h>
#include <hip/hip_bf16.h>

typedef __hip_bfloat16 bf16;
typedef __attribute__((ext_vector_type(8))) __bf16 bf16x8;
typedef __attribute__((ext_vector_type(4))) float f32x4;
typedef __attribute__((ext_vector_type(4))) unsigned int u32x4;

#define DEVI __device__ __forceinline__

DEVI float sigm(float x) { return 1.f / (1.f + __expf(-x)); }
DEVI float tanh_fast(float x) { float e = __expf(2.f * x); return 1.f - 2.f / (e + 1.f); }
DEVI float lo2f(unsigned u) { return __uint_as_float(u << 16); }
DEVI float hi2f(unsigned u) { return __uint_as_float(u & 0xffff0000u); }

DEVI __bf16 f2b(float f) {               // RNE f32->bf16
    unsigned u = __float_as_uint(f);
    u = u + 0x7FFFu + ((u >> 16) & 1u);
    unsigned short s = (unsigned short)(u >> 16);
    __bf16 b;
    __builtin_memcpy(&b, &s, 2);
    return b;
}
DEVI unsigned short b2u(__bf16 b) { unsigned short s; __builtin_memcpy(&s, &b, 2); return s; }

DEVI f32x4 MFMA(bf16x8 a, bf16x8 b, f32x4 c) {
    return __builtin_amdgcn_mfma_f32_16x16x32_bf16(a, b, c, 0, 0, 0);
}

DEVI bf16x8 load8(const bf16* p) { return *reinterpret_cast<const bf16x8*>(p); }
DEVI bf16x8 load8(const float* p) {
    float4 a = *reinterpret_cast<const float4*>(p);
    float4 b = *reinterpret_cast<const float4*>(p + 4);
    bf16x8 r;
    r[0] = f2b(a.x); r[1] = f2b(a.y); r[2] = f2b(a.z); r[3] = f2b(a.w);
    r[4] = f2b(b.x); r[5] = f2b(b.y); r[6] = f2b(b.z); r[7] = f2b(b.w);
    return r;
}

DEVI void storeOut(float* p, float v) { *p = v; }
DEVI void storeOut(bf16* p, float v) { *p = __float2bfloat16(v); }

// ---- coherent (cache-bypassing) memory ops via asm sc0 sc1 -----------------
#define WAIT_COHERENT() do { \
    asm volatile("s_waitcnt vmcnt(0)" ::: "memory"); \
    __builtin_amdgcn_sched_barrier(0); } while (0)

DEVI bf16x8 ld_cv16(const bf16* p) {
    u32x4 r;
    asm volatile("global_load_dwordx4 %0, %1, off sc0 sc1"
                 : "=v"(r) : "v"(p) : "memory");
    bf16x8 out;
    __builtin_memcpy(&out, &r, 16);
    return out;
}
DEVI f32x4 ld_cv16f(const float* p) {
    f32x4 r;
    asm volatile("global_load_dwordx4 %0, %1, off sc0 sc1"
                 : "=v"(r) : "v"(p) : "memory");
    return r;
}
DEVI unsigned ld_c_u32(const void* p) {
    unsigned r;
    asm volatile("global_load_dword %0, %1, off sc0 sc1"
                 : "=v"(r) : "v"(p) : "memory");
    return r;
}
DEVI void st_c_u32(void* p, unsigned v) {
    asm volatile("global_store_dword %0, %1, off sc0 sc1"
                 :: "v"(p), "v"(v) : "memory");
}

// ---------------------------------------------------------------------------
// Grid barrier: signal = atomic RMW (PROVEN r5-r12). Poll = coherent LOAD
// (non-serializing) with a periodic RMW fallback (the proven primitive) every
// 64 spins -> hang-proof even if bypass loads were to read stale data.
// ---------------------------------------------------------------------------
DEVI void gsync(unsigned* bar, unsigned target) {
    asm volatile("s_waitcnt vmcnt(0)" ::: "memory");
    __syncthreads();
    if (threadIdx.x == 0) {
        __hip_atomic_fetch_add(bar, 1u, __ATOMIC_RELAXED, __HIP_MEMORY_SCOPE_AGENT);
        unsigned it = 0;
        for (;;) {
            unsigned v = ld_c_u32(bar);
            WAIT_COHERENT();
            if (v >= target) break;
            if ((++it & 63u) == 0u) {                       // proven fallback
                if (atomicAdd(bar, 0u) >= target) break;
            }
            __builtin_amdgcn_s_sleep(2);
        }
    }
    asm volatile("" ::: "memory");
    __syncthreads();
}

// ---------------------------------------------------------------------------
// Generic MFMA GEMM: C[m*crs + n*ccs] = sum_k A[m,k]*B[n,k] (+bias[n]).
// ---------------------------------------------------------------------------
template<typename AT, typename BT, typename OT, bool GATHER, bool HASB>
__global__ __launch_bounds__(256)
void gemm_bt(const AT* __restrict__ A, const int* __restrict__ Aidx, int lda,
             const BT* __restrict__ B, int ldb, int boff,
             const float* __restrict__ bias,
             OT* __restrict__ C, long crs, long ccs,
             int M_real, int K)
{
    __shared__ __attribute__((aligned(16))) bf16 As[128 * 32];
    __shared__ __attribute__((aligned(16))) bf16 Bs[128 * 32];
    const int tid = threadIdx.x;
    const int lane = tid & 63;
    const int w = tid >> 6;
    const int wr = w >> 1, wc = w & 1;
    const int bm = blockIdx.y * 128;
    const int bn = blockIdx.x * 128;

    const int l16_0 = (2 * w + 0) * 64 + lane;
    const int l16_1 = (2 * w + 1) * 64 + lane;
    const int row0 = l16_0 >> 2, c0 = l16_0 & 3;
    const int row1 = l16_1 >> 2, c1 = l16_1 & 3;

    long arow0 = GATHER ? (long)Aidx[bm + row0] : (long)(bm + row0);
    long arow1 = GATHER ? (long)Aidx[bm + row1] : (long)(bm + row1);
    const AT* agp0 = A + arow0 * lda + c0 * 8;
    const AT* agp1 = A + arow1 * lda + c1 * 8;
    const BT* bgp0 = B + (long)(bn + row0) * ldb + boff + c0 * 8;
    const BT* bgp1 = B + (long)(bn + row1) * ldb + boff + c1 * 8;

    f32x4 acc[4][4];
    #pragma unroll
    for (int i = 0; i < 4; i++)
        #pragma unroll
        for (int j = 0; j < 4; j++) acc[i][j] = f32x4{0.f, 0.f, 0.f, 0.f};

    const bf16x8* Asv = reinterpret_cast<const bf16x8*>(As);
    const bf16x8* Bsv = reinterpret_cast<const bf16x8*>(Bs);
    bf16x8* AsW = reinterpret_cast<bf16x8*>(As);
    bf16x8* BsW = reinterpret_cast<bf16x8*>(Bs);
    const int kq = lane >> 4;
    const int lrow = lane & 15;

    bf16x8 ra0 = load8(agp0);
    bf16x8 ra1 = load8(agp1);
    bf16x8 rb0 = load8(bgp0);
    bf16x8 rb1 = load8(bgp1);

    for (int k0 = 0; k0 < K; k0 += 32) {
        __syncthreads();
        AsW[l16_0] = ra0; AsW[l16_1] = ra1;
        BsW[l16_0] = rb0; BsW[l16_1] = rb1;
        __syncthreads();

        const int kn = k0 + 32;
        if (kn < K) {
            ra0 = load8(agp0 + kn);
            ra1 = load8(agp1 + kn);
            rb0 = load8(bgp0 + kn);
            rb1 = load8(bgp1 + kn);
        }

        bf16x8 af[4], bfr[4];
        #pragma unroll
        for (int mt = 0; mt < 4; mt++) af[mt] = Asv[(wr * 64 + mt * 16 + lrow) * 4 + kq];
        #pragma unroll
        for (int nt = 0; nt < 4; nt++) bfr[nt] = Bsv[(wc * 64 + nt * 16 + lrow) * 4 + kq];
        #pragma unroll
        for (int mt = 0; mt < 4; mt++)
            #pragma unroll
            for (int nt = 0; nt < 4; nt++)
                acc[mt][nt] = MFMA(af[mt], bfr[nt], acc[mt][nt]);
    }

    const int rbase = kq * 4;
    #pragma unroll
    for (int nt = 0; nt < 4; nt++) {
        const int col = bn + wc * 64 + nt * 16 + lrow;
        float bv = 0.f;
        if (HASB) bv = bias[col];
        #pragma unroll
        for (int mt = 0; mt < 4; mt++) {
            const int rw = bm + wr * 64 + mt * 16 + rbase;
            #pragma unroll
            for (int r = 0; r < 4; r++) {
                const int row = rw + r;
                if (row < M_real) storeOut(&C[(long)row * crs + (long)col * ccs], acc[mt][nt][r] + bv);
            }
        }
    }
}

// ---------------------------------------------------------------------------
// FC GEMM: logits = H_all @ B^T + fc_b, XCD panel mapping. B templated
// (f32 source, inline-converted during reg staging).
// ---------------------------------------------------------------------------
template<typename BT>
__global__ __launch_bounds__(256)
void gemm_fc(const bf16* __restrict__ A, const BT* __restrict__ B,
             const float* __restrict__ bias, float* __restrict__ C)
{
    __shared__ __attribute__((aligned(16))) bf16 As[8192];
    __shared__ __attribute__((aligned(16))) bf16 Bs[8192];
    const int tid = threadIdx.x;
    const int bid = blockIdx.x;
    const int xcd = bid & 7;
    const int ii = bid >> 3;
    const int p = xcd + 8 * (ii >> 4);
    const int m = ii & 15;
    if (p >= 250) return;
    const int bm = m * 128, bn = p * 128;

    const int lane = tid & 63, w = tid >> 6, wr = w >> 1, wc = w & 1;
    const int kq = lane >> 4, lrow = lane & 15;

    int rowc[4], c8c[4];
    const bf16* gA[4];
    const BT* gB[4];
    #pragma unroll
    for (int c = 0; c < 4; c++) {
        int q = c * 256 + tid;
        rowc[c] = q >> 3; c8c[c] = q & 7;
        gA[c] = A + (long)(bm + rowc[c]) * 1024 + c8c[c] * 8;
        gB[c] = B + (long)(bn + rowc[c]) * 1024 + c8c[c] * 8;
    }

    f32x4 acc[4][4];
    #pragma unroll
    for (int i = 0; i < 4; i++)
        #pragma unroll
        for (int j = 0; j < 4; j++) acc[i][j] = f32x4{0.f, 0.f, 0.f, 0.f};

    bf16x8* AsW = reinterpret_cast<bf16x8*>(As);
    bf16x8* BsW = reinterpret_cast<bf16x8*>(Bs);
    const bf16x8* Asv = reinterpret_cast<const bf16x8*>(As);
    const bf16x8* Bsv = reinterpret_cast<const bf16x8*>(Bs);

    bf16x8 ra[4], rb[4];
    #pragma unroll
    for (int c = 0; c < 4; c++) { ra[c] = load8(gA[c]); rb[c] = load8(gB[c]); }

    for (int kt = 0; kt < 16; ++kt) {
        __syncthreads();
        #pragma unroll
        for (int c = 0; c < 4; c++) {
            AsW[c8c[c] * 128 + rowc[c]] = ra[c];
            BsW[c8c[c] * 128 + rowc[c]] = rb[c];
        }
        __syncthreads();
        if (kt < 15) {
            const int ko = (kt + 1) * 64;
            #pragma unroll
            for (int c = 0; c < 4; c++) { ra[c] = load8(gA[c] + ko); rb[c] = load8(gB[c] + ko); }
        }
        #pragma unroll
        for (int h = 0; h < 2; ++h) {
            bf16x8 af[4], bfr[4];
            #pragma unroll
            for (int mt = 0; mt < 4; mt++) af[mt] = Asv[(h * 4 + kq) * 128 + wr * 64 + mt * 16 + lrow];
            #pragma unroll
            for (int nt = 0; nt < 4; nt++) bfr[nt] = Bsv[(h * 4 + kq) * 128 + wc * 64 + nt * 16 + lrow];
            #pragma unroll
            for (int mt = 0; mt < 4; mt++)
                #pragma unroll
                for (int nt = 0; nt < 4; nt++)
                    acc[mt][nt] = MFMA(af[mt], bfr[nt], acc[mt][nt]);
        }
    }

    const int rbase = kq * 4;
    #pragma unroll
    for (int nt = 0; nt < 4; nt++) {
        const int col = bn + wc * 64 + nt * 16 + lrow;
        const float bv = bias[col];
        #pragma unroll
        for (int mt = 0; mt < 4; mt++) {
            const int rw = bm + wr * 64 + mt * 16 + rbase;
            #pragma unroll
            for (int r = 0; r < 4; r++) {
                const int row = rw + r;
                if (row < 2016) C[(long)row * 32000 + col] = acc[mt][nt][r] + bv;
            }
        }
    }
}

// ---------------------------------------------------------------------------
__global__ __launch_bounds__(256)
void cvt_f32_bf16(const float* __restrict__ in, bf16* __restrict__ out, int n)
{
    int i = (blockIdx.x * blockDim.x + threadIdx.x) * 4;
    if (i < n) {
        float4 v = *reinterpret_cast<const float4*>(in + i);
        ushort4 o;
        o.x = b2u(f2b(v.x)); o.y = b2u(f2b(v.y));
        o.z = b2u(f2b(v.z)); o.w = b2u(f2b(v.w));
        *reinterpret_cast<ushort4*>(out + i) = o;
    }
}

// Wh_bf[e][k] = bf16(attn_W[e][k]) for k<1024 (attn_W is [512][2048])
__global__ __launch_bounds__(256)
void cvt_wh(const float* __restrict__ in, bf16* __restrict__ out)
{
    int i = (blockIdx.x * blockDim.x + threadIdx.x) * 4;
    if (i < 524288) {
        int e = i >> 10, k = i & 1023;
        float4 v = *reinterpret_cast<const float4*>(in + (size_t)e * 2048 + k);
        ushort4 o;
        o.x = b2u(f2b(v.x)); o.y = b2u(f2b(v.y));
        o.z = b2u(f2b(v.z)); o.w = b2u(f2b(v.w));
        *reinterpret_cast<ushort4*>(out + i) = o;
    }
}

// ---------------------------------------------------------------------------
// Persistent encoder (r12 structure, decontended barrier).
// ---------------------------------------------------------------------------
__global__ __launch_bounds__(512, 1)
void enc_persist(bf16* __restrict__ h_bf,
                 const float* __restrict__ X,
                 const bf16* __restrict__ Whh, const float* __restrict__ bhh,
                 bf16* __restrict__ enc_out,
                 unsigned* __restrict__ bar)
{
    __shared__ float part[8][3][32][33];
    const int tid = threadIdx.x;
    const int lane = tid & 63;
    const int kw = tid >> 6;
    const int lrow = lane & 15;
    const int kq = lane >> 4;
    const int j0 = blockIdx.x * 32;

    const bf16x8* wv = reinterpret_cast<const bf16x8*>(Whh);
    bf16x8 wB[3][2][4];
    #pragma unroll
    for (int g = 0; g < 3; g++)
        #pragma unroll
        for (int jt = 0; jt < 2; jt++)
            #pragma unroll
            for (int kk = 0; kk < 4; kk++)
                wB[g][jt][kk] = wv[(size_t)(g * 1024 + j0 + jt * 16 + lrow) * 128 + kw * 16 + kq + kk * 4];

    const int bb = tid >> 4;
    const int jp = tid & 15;
    float bh[3][2];
    #pragma unroll
    for (int g = 0; g < 3; g++) {
        bh[g][0] = bhh[g * 1024 + j0 + jp * 2];
        bh[g][1] = bhh[g * 1024 + j0 + jp * 2 + 1];
    }
    float hprev[2] = {0.f, 0.f};
    unsigned sn = 0;

    for (int t = 0; t < 64; ++t) {
        const int cur = t & 1;
        const bf16* hbuf = h_bf + cur * 32768;

        bf16x8 af[2][4];
        #pragma unroll
        for (int bt = 0; bt < 2; bt++)
            #pragma unroll
            for (int kk = 0; kk < 4; kk++)
                af[bt][kk] = ld_cv16(hbuf + ((size_t)(bt * 16 + lrow) * 128 + kw * 16 + kq + kk * 4) * 8);

        const size_t xb = ((size_t)bb * 64 + t) * 3072 + j0 + jp * 2;
        float2 xg0 = *reinterpret_cast<const float2*>(X + xb);
        float2 xg1 = *reinterpret_cast<const float2*>(X + xb + 1024);
        float2 xg2 = *reinterpret_cast<const float2*>(X + xb + 2048);
        WAIT_COHERENT();

        f32x4 acc[3][2][2];
        #pragma unroll
        for (int g = 0; g < 3; g++)
            #pragma unroll
            for (int jt = 0; jt < 2; jt++)
                #pragma unroll
                for (int bt = 0; bt < 2; bt++) acc[g][jt][bt] = f32x4{0, 0, 0, 0};
        #pragma unroll
        for (int kk = 0; kk < 4; kk++)
            #pragma unroll
            for (int g = 0; g < 3; g++)
                #pragma unroll
                for (int jt = 0; jt < 2; jt++) {
                    acc[g][jt][0] = MFMA(af[0][kk], wB[g][jt][kk], acc[g][jt][0]);
                    acc[g][jt][1] = MFMA(af[1][kk], wB[g][jt][kk], acc[g][jt][1]);
                }
        #pragma unroll
        for (int g = 0; g < 3; g++)
            #pragma unroll
            for (int jt = 0; jt < 2; jt++)
                #pragma unroll
                for (int bt = 0; bt < 2; bt++)
                    #pragma unroll
                    for (int r = 0; r < 4; r++)
                        part[kw][g][bt * 16 + kq * 4 + r][jt * 16 + lrow] = acc[g][jt][bt][r];
        __syncthreads();

        float h2o[2];
        #pragma unroll
        for (int o = 0; o < 2; ++o) {
            const int jc = jp * 2 + o;
            float s0 = 0.f, s1 = 0.f, s2 = 0.f;
            #pragma unroll
            for (int ww = 0; ww < 8; ww++) {
                s0 += part[ww][0][bb][jc];
                s1 += part[ww][1][bb][jc];
                s2 += part[ww][2][bb][jc];
            }
            float x0 = o ? xg0.y : xg0.x;
            float x1 = o ? xg1.y : xg1.x;
            float x2 = o ? xg2.y : xg2.x;
            float rr = sigm(x0 + s0 + bh[0][o]);
            float zz = sigm(x1 + s1 + bh[1][o]);
            float nn = tanh_fast(x2 + rr * (s2 + bh[2][o]));
            h2o[o] = (1.f - zz) * nn + zz * hprev[o];
            hprev[o] = h2o[o];
        }
        unsigned pk = (unsigned)b2u(f2b(h2o[0])) | ((unsigned)b2u(f2b(h2o[1])) << 16);
        st_c_u32(h_bf + (cur ^ 1) * 32768 + bb * 1024 + j0 + jp * 2, pk);
        *reinterpret_cast<unsigned*>(enc_out + ((size_t)bb * 64 + t) * 1024 + j0 + jp * 2) = pk;

        if (t < 63) gsync(bar, ++sn * 32);
    }
}

// ---------------------------------------------------------------------------
// Persistent decoder (r12 structure; P1 hosts the GRU MFMA so P3's critical
// path is minimal; a_gT publish issued before the MFMA to hide store latency).
// ---------------------------------------------------------------------------
__global__ __launch_bounds__(512, 1)
void dec_persist(bf16* __restrict__ h_bf,
                 const float* __restrict__ X,
                 const bf16* __restrict__ Whh, const float* __restrict__ bhh,
                 const bf16* __restrict__ encT0,   // [2048 m][1024 j] per gate
                 const bf16* __restrict__ encT1,
                 const bf16* __restrict__ encT2,
                 bf16* __restrict__ Hall,
                 const bf16* __restrict__ Wh_bf,   // [512][1024] bf16
                 const bf16* __restrict__ enc_pj,  // [2048 m][512 e] bf16
                 const float* __restrict__ v_w,
                 float* __restrict__ a_gT,         // [32 b][512 e] f32
                 float* __restrict__ w_g,          // [32 b][64 s] f32
                 unsigned* __restrict__ bar)
{
    __shared__ float part[8][3][32][33];      // ~101 KB
    __shared__ float apart[8][16][32];        // 16 KB
    __shared__ __attribute__((aligned(16))) float a_ls[512];
    __shared__ __attribute__((aligned(16))) float w_s[2048];   // [32][64]
    __shared__ float sc_s[64];

    const int tid = threadIdx.x;
    const int lane = tid & 63;
    const int kw = tid >> 6;
    const int lrow = lane & 15;
    const int kq = lane >> 4;
    const int j0 = blockIdx.x * 32;
    const int e0 = blockIdx.x * 16;           // a e-slice
    const int b = blockIdx.x;                 // attention batch

    // hoisted Whh fragments (96 VGPR)
    const bf16x8* wv = reinterpret_cast<const bf16x8*>(Whh);
    bf16x8 wB[3][2][4];
    #pragma unroll
    for (int g = 0; g < 3; g++)
        #pragma unroll
        for (int jt = 0; jt < 2; jt++)
            #pragma unroll
            for (int kk = 0; kk < 4; kk++)
                wB[g][jt][kk] = wv[(size_t)(g * 1024 + j0 + jt * 16 + lrow) * 128 + kw * 16 + kq + kk * 4];

    // hoisted Wh A-fragments for a-MFMA (16 VGPR)
    const bf16x8* whv = reinterpret_cast<const bf16x8*>(Wh_bf);
    bf16x8 whA[4];
    #pragma unroll
    for (int kk = 0; kk < 4; kk++)
        whA[kk] = whv[(size_t)(e0 + lrow) * 128 + kw * 16 + kq + kk * 4];

    // hoisted v_w chunk: e = lane*8 + ii
    float vr[8];
    #pragma unroll
    for (int ii = 0; ii < 8; ii++) vr[ii] = v_w[lane * 8 + ii];

    const int bb = tid >> 4;
    const int jp = tid & 15;
    float bh[3][2];
    #pragma unroll
    for (int g = 0; g < 3; g++) {
        bh[g][0] = bhh[g * 1024 + j0 + jp * 2];
        bh[g][1] = bhh[g * 1024 + j0 + jp * 2 + 1];
    }

    // seed hprev from h_last (encoder's final publish, buffer 0)
    float hprev[2];
    {
        unsigned pk0 = ld_c_u32(h_bf + bb * 1024 + j0 + jp * 2);
        WAIT_COHERENT();
        hprev[0] = lo2f(pk0);
        hprev[1] = hi2f(pk0);
    }
    unsigned sn = 0;
    const bf16* encT[3] = {encT0, encT1, encT2};

    for (int t = 0; t < 63; ++t) {
        const int cur = t & 1;
        const bf16* hbuf = h_bf + cur * 32768;

        // ========== P1: h-frags + a-MFMA + publish a; then X prefetch + GRU MFMA
        bf16x8 af[2][4];
        #pragma unroll
        for (int bt = 0; bt < 2; bt++)
            #pragma unroll
            for (int kk = 0; kk < 4; kk++)
                af[bt][kk] = ld_cv16(hbuf + ((size_t)(bt * 16 + lrow) * 128 + kw * 16 + kq + kk * 4) * 8);
        WAIT_COHERENT();

        {
            f32x4 aa[2] = {f32x4{0,0,0,0}, f32x4{0,0,0,0}};
            #pragma unroll
            for (int kk = 0; kk < 4; kk++) {
                aa[0] = MFMA(whA[kk], af[0][kk], aa[0]);
                aa[1] = MFMA(whA[kk], af[1][kk], aa[1]);
            }
            #pragma unroll
            for (int bt = 0; bt < 2; bt++)
                #pragma unroll
                for (int r = 0; r < 4; r++)
                    apart[kw][kq * 4 + r][bt * 16 + lrow] = aa[bt][r];
        }
        __syncthreads();
        {
            const int e = tid >> 5, bq = tid & 31;
            float s = 0.f;
            #pragma unroll
            for (int ww = 0; ww < 8; ww++) s += apart[ww][e][bq];
            st_c_u32(a_gT + (size_t)bq * 512 + e0 + e, __float_as_uint(s));
        }

        // X prefetch for P3 (held in registers across two barriers)
        const size_t xb = ((size_t)bb * 63 + t) * 3072 + j0 + jp * 2;
        float2 xg0 = *reinterpret_cast<const float2*>(X + xb);
        float2 xg1 = *reinterpret_cast<const float2*>(X + xb + 1024);
        float2 xg2 = *reinterpret_cast<const float2*>(X + xb + 2048);

        // GRU-gates MFMA (result needed only in P3; store latency of a_gT
        // and X loads hide under this compute)
        f32x4 acc[3][2][2];
        #pragma unroll
        for (int g = 0; g < 3; g++)
            #pragma unroll
            for (int jt = 0; jt < 2; jt++)
                #pragma unroll
                for (int bt = 0; bt < 2; bt++) acc[g][jt][bt] = f32x4{0, 0, 0, 0};
        #pragma unroll
        for (int kk = 0; kk < 4; kk++)
            #pragma unroll
            for (int g = 0; g < 3; g++)
                #pragma unroll
                for (int jt = 0; jt < 2; jt++) {
                    acc[g][jt][0] = MFMA(af[0][kk], wB[g][jt][kk], acc[g][jt][0]);
                    acc[g][jt][1] = MFMA(af[1][kk], wB[g][jt][kk], acc[g][jt][1]);
                }
        #pragma unroll
        for (int g = 0; g < 3; g++)
            #pragma unroll
            for (int jt = 0; jt < 2; jt++)
                #pragma unroll
                for (int bt = 0; bt < 2; bt++)
                    #pragma unroll
                    for (int r = 0; r < 4; r++)
                        part[kw][g][bt * 16 + kq * 4 + r][jt * 16 + lrow] = acc[g][jt][bt][r];
        gsync(bar, ++sn * 32);

        // ========== P2: coalesced a-gather + scores + softmax + publish w ===
        {
            unsigned av = ld_c_u32(a_gT + (size_t)b * 512 + tid);   // coalesced
            WAIT_COHERENT();
            a_ls[tid] = __uint_as_float(av);
        }
        __syncthreads();
        #pragma unroll
        for (int si = 0; si < 8; ++si) {
            const int s = kw * 8 + si;
            u32x4 u = *reinterpret_cast<const u32x4*>(enc_pj + ((size_t)b * 64 + s) * 512 + lane * 8);
            float p = 0.f;
            #pragma unroll
            for (int i = 0; i < 4; ++i) {
                p += vr[2 * i]     * tanh_fast(lo2f(u[i]) + a_ls[lane * 8 + 2 * i]);
                p += vr[2 * i + 1] * tanh_fast(hi2f(u[i]) + a_ls[lane * 8 + 2 * i + 1]);
            }
            #pragma unroll
            for (int off = 32; off; off >>= 1) p += __shfl_xor(p, off);
            if (lane == 0) sc_s[s] = p;
        }
        __syncthreads();
        if (tid < 64) {
            float v = sc_s[tid], m = v;
            #pragma unroll
            for (int off = 32; off; off >>= 1) m = fmaxf(m, __shfl_xor(m, off));
            float e = __expf(v - m);
            float su = e;
            #pragma unroll
            for (int off = 32; off; off >>= 1) su += __shfl_xor(su, off);
            st_c_u32(w_g + b * 64 + tid, __float_as_uint(e / su));
        }
        gsync(bar, ++sn * 32);

        // ========== P3: w-load + ctx-dot + pointwise + publish h ============
        f32x4 wld = ld_cv16f(w_g + tid * 4);
        WAIT_COHERENT();
        *reinterpret_cast<f32x4*>(&w_s[tid * 4]) = wld;
        __syncthreads();

        // ctx-dot: c[g][o] = sum_s w[bb,s] * encT[g][bb*64+s][j0+jp*2+o]
        float c0[3] = {0, 0, 0}, c1[3] = {0, 0, 0};
        #pragma unroll
        for (int g = 0; g < 3; g++) {
            const bf16* base = encT[g] + (size_t)bb * 64 * 1024 + j0 + jp * 2;
            #pragma unroll 8
            for (int s = 0; s < 64; ++s) {
                unsigned u = *reinterpret_cast<const unsigned*>(base + (size_t)s * 1024);
                float w = w_s[bb * 64 + s];
                c0[g] += lo2f(u) * w;
                c1[g] += hi2f(u) * w;
            }
        }

        float h2o[2];
        #pragma unroll
        for (int o = 0; o < 2; ++o) {
            const int jc = jp * 2 + o;
            float g0 = 0.f, g1 = 0.f, g2 = 0.f;
            #pragma unroll
            for (int ww = 0; ww < 8; ww++) {
                g0 += part[ww][0][bb][jc];
                g1 += part[ww][1][bb][jc];
                g2 += part[ww][2][bb][jc];
            }
            float cc0 = o ? c1[0] : c0[0];
            float cc1 = o ? c1[1] : c0[1];
            float cc2 = o ? c1[2] : c0[2];
            float x0 = o ? xg0.y : xg0.x;
            float x1 = o ? xg1.y : xg1.x;
            float x2 = o ? xg2.y : xg2.x;
            float rr = sigm(x0 + cc0 + g0 + bh[0][o]);
            float zz = sigm(x1 + cc1 + g1 + bh[1][o]);
            float nn = tanh_fast(x2 + cc2 + rr * (g2 + bh[2][o]));
            h2o[o] = (1.f - zz) * nn + zz * hprev[o];
            hprev[o] = h2o[o];
        }
        unsigned pk = (unsigned)b2u(f2b(h2o[0])) | ((unsigned)b2u(f2b(h2o[1])) << 16);
        st_c_u32(h_bf + (cur ^ 1) * 32768 + bb * 1024 + j0 + jp * 2, pk);
        *reinterpret_cast<unsigned*>(Hall + ((size_t)bb * 63 + t) * 1024 + j0 + jp * 2) = pk;

        if (t < 62) gsync(bar, ++sn * 32);
    }
}

// ---------------------------------------------------------------------------
__global__ void init_k(bf16* __restrict__ h0, bf16* __restrict__ hall_pad,
                       int* __restrict__ idx_dec,
                       const int* __restrict__ tgt, unsigned* __restrict__ bar)
{
    const int i = blockIdx.x * blockDim.x + threadIdx.x;
    if (i < 64) bar[i] = 0u;
    if (i < 32768) {
        h0[i] = __float2bfloat16(0.f);
        hall_pad[i] = __float2bfloat16(0.f);
    }
    if (i < 2048) {
        int v = 0;
        if (i < 2016) { int bq = i / 63; int tq = i - bq * 63; v = tgt[bq * 64 + tq]; }
        idx_dec[i] = v;
    }
}

// ---------------------------------------------------------------------------
extern "C" void kernel_launch(void* const* d_in, const int* in_sizes, int n_in,
                              void* d_out, int out_size, void* d_ws, size_t ws_size,
                              hipStream_t stream)
{
    const int*   src       = (const int*)d_in[0];
    const int*   tgt       = (const int*)d_in[1];
    const float* src_embed = (const float*)d_in[2];
    const float* tgt_embed = (const float*)d_in[3];
    const float* enc_Wih   = (const float*)d_in[4];
    const float* enc_Whh   = (const float*)d_in[5];
    const float* enc_bih   = (const float*)d_in[6];
    const float* enc_bhh   = (const float*)d_in[7];
    const float* dec_Wih   = (const float*)d_in[8];
    const float* dec_Whh   = (const float*)d_in[9];
    const float* dec_bih   = (const float*)d_in[10];
    const float* dec_bhh   = (const float*)d_in[11];
    const float* attn_W    = (const float*)d_in[12];
    const float* attn_b    = (const float*)d_in[13];
    const float* v_w       = (const float*)d_in[14];
    const float* fc_W      = (const float*)d_in[15];
    const float* fc_b      = (const float*)d_in[16];

    char* w = (char*)d_ws;
    unsigned* bar      = (unsigned*)(w);             // [64]
    float* X_enc       = (float*)(w + 256);          // [2048][3072] f32
    float* X_dec       = (float*)(w + 25166080);     // [2048][3072] f32
    bf16*  enc_bf      = (bf16*) (w + 50331904);     // [2048][1024]
    bf16*  enc_pj_bf   = (bf16*) (w + 54526208);     // [2048][512]
    bf16*  H_all       = (bf16*) (w + 56623360);     // [2048][1024]
    bf16*  h_bf        = (bf16*) (w + 60817664);     // 2 x [32][1024]
    float* w_g         = (float*)(w + 60948736);     // [32][64]
    float* a_gT        = (float*)(w + 60956928);     // [32][512]
    int*   idx_dec     = (int*)  (w + 61022464);     // [2048]
    bf16*  enc_Whh_bf  = (bf16*) (w + 61030656);     // [3072][1024]
    bf16*  dec_Whh_bf  = (bf16*) (w + 67322112);     // [3072][1024]
    bf16*  Wh_bf       = (bf16*) (w + 73613568);     // [512][1024]
    bf16*  encT0       = (bf16*) (w + 74662144);     // [2048][1024]
    bf16*  encT1       = (bf16*) (w + 78856448);     // [2048][1024]
    bf16*  encT2       = (bf16*) (w + 83050752);     // [2048][1024]
    // total: 87,245,056 bytes

    init_k<<<128, 256, 0, stream>>>(h_bf, H_all + 2016 * 1024, idx_dec, tgt, bar);
    cvt_f32_bf16<<<3072, 256, 0, stream>>>(enc_Whh, enc_Whh_bf, 3145728);
    cvt_f32_bf16<<<3072, 256, 0, stream>>>(dec_Whh, dec_Whh_bf, 3145728);
    cvt_wh<<<512, 256, 0, stream>>>(attn_W, Wh_bf);

    // X_enc = gather(src_embed, src) @ enc_Wih^T + enc_bih
    gemm_bt<float, float, float, true, true><<<dim3(24, 16), 256, 0, stream>>>(
        src_embed, src, 512, enc_Wih, 512, 0, enc_bih, X_enc, 3072, 1, 2048, 512);
    // X_dec = gather(tgt_embed, tgt[:, :-1]) @ dec_Wih[:, :512]^T + dec_bih
    gemm_bt<float, float, float, true, true><<<dim3(24, 16), 256, 0, stream>>>(
        tgt_embed, idx_dec, 512, dec_Wih, 1536, 0, dec_bih, X_dec, 3072, 1, 2048, 512);

    // encoder: persistent
    enc_persist<<<32, 512, 0, stream>>>(h_bf, X_enc, enc_Whh_bf, enc_bhh, enc_bf, bar);

    // enc_proj(bf16) = enc @ We^T + attn_b
    gemm_bt<bf16, float, bf16, false, true><<<dim3(4, 16), 256, 0, stream>>>(
        enc_bf, nullptr, 1024, attn_W, 2048, 1024, attn_b, enc_pj_bf, 512, 1, 2048, 1024);

    // encT[g][m][j] = enc @ dec_Wih[g-gate rows, 512:]^T   (j contiguous)
    gemm_bt<bf16, float, bf16, false, false><<<dim3(8, 16), 256, 0, stream>>>(
        enc_bf, nullptr, 1024, dec_Wih + (size_t)0 * 1024 * 1536, 1536, 512, nullptr, encT0, 1024, 1, 2048, 1024);
    gemm_bt<bf16, float, bf16, false, false><<<dim3(8, 16), 256, 0, stream>>>(
        enc_bf, nullptr, 1024, dec_Wih + (size_t)1 * 1024 * 1536, 1536, 512, nullptr, encT1, 1024, 1, 2048, 1024);
    gemm_bt<bf16, float, bf16, false, false><<<dim3(8, 16), 256, 0, stream>>>(
        enc_bf, nullptr, 1024, dec_Wih + (size_t)2 * 1024 * 1536, 1536, 512, nullptr, encT2, 1024, 1, 2048, 1024);

    // decoder: persistent (3 barriers/step, decontended poll)
    dec_persist<<<32, 512, 0, stream>>>(h_bf, X_dec, dec_Whh_bf, dec_bhh,
                                        encT0, encT1, encT2,
                                        H_all, Wh_bf, enc_pj_bf, v_w,
                                        a_gT, w_g, bar + 32);

    // logits = H_all @ fc_W^T (f32 B, inline cvt) + fc_b -> d_out (f32)
    gemm_fc<float><<<4096, 256, 0, stream>>>(H_all, fc_W, fc_b, (float*)d_out);
}